// Round 1
// baseline (1063.459 us; speedup 1.0000x reference)
//
#include <hip/hip_runtime.h>
#include <hip/hip_bf16.h>
#include <math.h>

// GAT forward, fp32 correctness-first implementation.
// N=4096 nodes, Fin=512, H=8 heads, D=64, C=64.
// Pipeline:
//  1. pack adj -> 64-bit masks            (2 MB, read 9x from L2 instead of 67MB x9 from HBM)
//  2. Wh1 = x @ W (all heads)             [4096,512] fp32 tiled GEMM
//  3. f1,f2 per head (64-dot per row), gmax = max(f2)
//  4. flash-style masked softmax attention + ELU -> h [4096,512]
//  5. Who = h @ Wo, f/gmax, attention + ELU -> attout [4096,64]
//  6. column log_softmax (axis 0, in place)
//  7. y1 = leaky(ls^T @ W1^T), y2 = y1 @ W2^T -> d_out [64,256]

#define N_NODES 4096
#define FIN 512
#define NHEAD 8
#define DHEAD 64
#define NCLS 64
#define NW 64  // 64-bit mask words per row

__device__ __forceinline__ float lrelu02(float x) { return x > 0.f ? x : 0.2f * x; }

// ---------------- 1. adjacency -> bitmask ----------------
__global__ void pack_mask(const int* __restrict__ adj, unsigned long long* __restrict__ mb) {
    int nwaves = (gridDim.x * blockDim.x) >> 6;
    int wid = (blockIdx.x * blockDim.x + threadIdx.x) >> 6;
    int lane = threadIdx.x & 63;
    for (int w = wid; w < N_NODES * NW; w += nwaves) {
        int i = w >> 6, wc = w & 63;
        int j = (wc << 6) | lane;
        unsigned long long m = __ballot(adj[(size_t)i * N_NODES + j] > 0);
        if (lane == 0) mb[w] = m;
    }
}

// ---------------- 2. fp32 tiled GEMM, 64x64 tile ----------------
// BMODE 0: B row-major [K][ldb].  BMODE 1: B = W[H][Fin][D], col = head*64+d.
template <int BMODE>
__global__ __launch_bounds__(256) void gemm64(
    const float* __restrict__ A, const float* __restrict__ B, float* __restrict__ C,
    int M, int Ncols, int K, int lda, int ldb, int ldc) {
    __shared__ alignas(16) float As[16][68];
    __shared__ alignas(16) float Bs[16][68];
    int t = threadIdx.x;
    int bn = blockIdx.x * 64;
    int bm = blockIdx.y * 64;
    int tx = t & 15, ty = t >> 4;
    float acc[4][4] = {};
    int ra = t >> 2;          // 0..63  (A row within tile)
    int ka = (t & 3) * 4;     // 0,4,8,12
    int nb = t & 63;
    for (int k0 = 0; k0 < K; k0 += 16) {
        __syncthreads();
        float4 av = *(const float4*)(A + (size_t)(bm + ra) * lda + k0 + ka);
        As[ka + 0][ra] = av.x; As[ka + 1][ra] = av.y;
        As[ka + 2][ra] = av.z; As[ka + 3][ra] = av.w;
        #pragma unroll
        for (int u = 0; u < 4; ++u) {
            int kb = (t >> 6) + u * 4;
            float bv;
            if (BMODE == 1) {
                int col = bn + nb;
                bv = B[(size_t)(col >> 6) * (FIN * DHEAD) + (size_t)(k0 + kb) * DHEAD + (col & 63)];
            } else {
                bv = B[(size_t)(k0 + kb) * ldb + bn + nb];
            }
            Bs[kb][nb] = bv;
        }
        __syncthreads();
        #pragma unroll
        for (int kk = 0; kk < 16; ++kk) {
            float4 a4 = *(const float4*)(&As[kk][ty * 4]);
            float4 b4 = *(const float4*)(&Bs[kk][tx * 4]);
            float aa[4] = {a4.x, a4.y, a4.z, a4.w};
            float bb[4] = {b4.x, b4.y, b4.z, b4.w};
            #pragma unroll
            for (int u = 0; u < 4; ++u)
                #pragma unroll
                for (int v = 0; v < 4; ++v) acc[u][v] = fmaf(aa[u], bb[v], acc[u][v]);
        }
    }
    #pragma unroll
    for (int u = 0; u < 4; ++u)
        #pragma unroll
        for (int v = 0; v < 4; ++v)
            C[(size_t)(bm + ty * 4 + u) * ldc + bn + tx * 4 + v] = acc[u][v];
}

// ---------------- 3. f1/f2 per row ----------------
__global__ __launch_bounds__(256) void f1f2k(
    const float* __restrict__ Wh, int ldwh, int whstep,
    const float* __restrict__ a1a, const float* __restrict__ a2a,
    float* __restrict__ f1o, float* __restrict__ f2o) {
    int h = blockIdx.y;
    int wv = threadIdx.x >> 6, lane = threadIdx.x & 63;
    int row = blockIdx.x * 4 + wv;
    const float* a1 = a1a + h * DHEAD;
    const float* a2 = a2a + h * DHEAD;
    float w = Wh[(size_t)row * ldwh + h * whstep + lane];
    float s1 = w * a1[lane];
    float s2 = w * a2[lane];
    #pragma unroll
    for (int off = 32; off; off >>= 1) {
        s1 += __shfl_xor(s1, off, 64);
        s2 += __shfl_xor(s2, off, 64);
    }
    if (lane == 0) {
        f1o[(size_t)h * N_NODES + row] = s1;
        f2o[(size_t)h * N_NODES + row] = s2;
    }
}

__global__ void gmaxk(const float* __restrict__ f2, float* __restrict__ gm) {
    int h = blockIdx.x;
    __shared__ float r[256];
    float m = -1e30f;
    for (int i = threadIdx.x; i < N_NODES; i += 256) m = fmaxf(m, f2[(size_t)h * N_NODES + i]);
    r[threadIdx.x] = m;
    __syncthreads();
    for (int s = 128; s; s >>= 1) {
        if (threadIdx.x < s) r[threadIdx.x] = fmaxf(r[threadIdx.x], r[threadIdx.x + s]);
        __syncthreads();
    }
    if (threadIdx.x == 0) gm[h] = r[0];
}

// ---------------- 4. streamed masked-softmax attention + ELU ----------------
// Block: 256 threads = (64 d-lanes) x (4 y). Block owns 16 rows; thread owns
// rows {y, 4+y, 8+y, 12+y} at column d. Streams 64-wide j tiles.
__global__ __launch_bounds__(256) void attn64(
    const float* __restrict__ Wh, int ldwh, int whstep,
    const float* __restrict__ f1a, const float* __restrict__ f2a,
    const float* __restrict__ gmaxa, const unsigned long long* __restrict__ mb,
    float* __restrict__ outp, int ldo, int ostep) {
    __shared__ alignas(16) float WhT[64][64];  // [j_local][d]
    __shared__ float f2s[64];
    __shared__ alignas(16) float pS[16][64];   // [row_local][j_local]
    const int h = blockIdx.y;
    const int t = threadIdx.x;
    const int d = t & 63;
    const int y = t >> 6;
    const int i0 = blockIdx.x * 16;
    const float* __restrict__ f1 = f1a + (size_t)h * N_NODES;
    const float* __restrict__ f2 = f2a + (size_t)h * N_NODES;
    const float gmax = gmaxa[h];
    const int whc = h * whstep;
    const int oc = h * ostep;

    float f1r[4], negM[4];
    #pragma unroll
    for (int q = 0; q < 4; ++q) {
        float v = f1[i0 + q * 4 + y];
        f1r[q] = v;
        negM[q] = -lrelu02(v + gmax);
    }
    float acc[4] = {0, 0, 0, 0}, den[4] = {0, 0, 0, 0};

    const int jl0 = t >> 4;          // 0..15
    const int dd4 = (t & 15) * 4;    // 0..60

    for (int jt = 0; jt < 64; ++jt) {
        __syncthreads();  // prev PV done: safe to overwrite tiles
        #pragma unroll
        for (int r = 0; r < 4; ++r) {
            int jl = jl0 + r * 16;
            float4 v = *(const float4*)(Wh + (size_t)(jt * 64 + jl) * ldwh + whc + dd4);
            *(float4*)(&WhT[jl][dd4]) = v;
        }
        if (t < 64) f2s[t] = f2[jt * 64 + t];
        __syncthreads();
        // p-phase: thread computes p for (row q*4+y, l=d)
        #pragma unroll
        for (int q = 0; q < 4; ++q) {
            int row = q * 4 + y;
            unsigned long long w = mb[(size_t)(i0 + row) * NW + jt];
            float s = lrelu02(f1r[q] + f2s[d]);
            float p = ((w >> d) & 1ULL) ? __expf(s + negM[q]) : 0.f;
            den[q] += p;
            pS[row][d] = p;
        }
        __syncthreads();
        // PV: acc[q] += sum_l p[rowq][l] * Wh[l][d]
        #pragma unroll
        for (int l4 = 0; l4 < 16; ++l4) {
            float pq[4][4];
            #pragma unroll
            for (int q = 0; q < 4; ++q)
                *(float4*)pq[q] = *(const float4*)(&pS[q * 4 + y][l4 * 4]);
            #pragma unroll
            for (int u = 0; u < 4; ++u) {
                float wh = WhT[l4 * 4 + u][d];
                #pragma unroll
                for (int q = 0; q < 4; ++q) acc[q] = fmaf(pq[q][u], wh, acc[q]);
            }
        }
    }
    // denominator: reduce the per-lane (fixed l=d) partials across the wave
    #pragma unroll
    for (int q = 0; q < 4; ++q)
        #pragma unroll
        for (int off = 32; off; off >>= 1) den[q] += __shfl_xor(den[q], off, 64);
    #pragma unroll
    for (int q = 0; q < 4; ++q) {
        int row = i0 + q * 4 + y;
        float v = den[q] > 0.f ? acc[q] / den[q] : 0.f;
        v = v > 0.f ? v : expm1f(v);  // ELU
        outp[(size_t)row * ldo + oc + d] = v;
    }
}

// ---------------- 6. column log_softmax, in place ----------------
__global__ void lsm_col(float* __restrict__ o) {
    int c = blockIdx.x, t = threadIdx.x;
    __shared__ float r[256];
    float m = -1e30f;
    for (int i = t; i < N_NODES; i += 256) m = fmaxf(m, o[(size_t)i * NCLS + c]);
    r[t] = m;
    __syncthreads();
    for (int s = 128; s; s >>= 1) {
        if (t < s) r[t] = fmaxf(r[t], r[t + s]);
        __syncthreads();
    }
    m = r[0];
    __syncthreads();
    float sum = 0.f;
    for (int i = t; i < N_NODES; i += 256) sum += __expf(o[(size_t)i * NCLS + c] - m);
    r[t] = sum;
    __syncthreads();
    for (int s = 128; s; s >>= 1) {
        if (t < s) r[t] += r[t + s];
        __syncthreads();
    }
    float lse = m + __logf(r[0]);
    for (int i = t; i < N_NODES; i += 256) o[(size_t)i * NCLS + c] -= lse;
}

// ---------------- 7. MLP head ----------------
// y1[c][o] = leaky( sum_i ls[i][c] * W1[o][i] + b1[o], 0.1 )
__global__ __launch_bounds__(256) void mlp1(
    const float* __restrict__ ls, const float* __restrict__ W1,
    const float* __restrict__ b1, float* __restrict__ y1) {
    int wv = threadIdx.x >> 6, c = threadIdx.x & 63;
    int o = blockIdx.x * 4 + wv;
    float acc = 0.f;
    for (int i = 0; i < N_NODES; i += 4) {
        float4 w4 = *(const float4*)(W1 + (size_t)o * N_NODES + i);
        acc = fmaf(w4.x, ls[(size_t)(i + 0) * NCLS + c], acc);
        acc = fmaf(w4.y, ls[(size_t)(i + 1) * NCLS + c], acc);
        acc = fmaf(w4.z, ls[(size_t)(i + 2) * NCLS + c], acc);
        acc = fmaf(w4.w, ls[(size_t)(i + 3) * NCLS + c], acc);
    }
    acc += b1[o];
    acc = acc > 0.f ? acc : 0.1f * acc;
    y1[(size_t)c * 512 + o] = acc;
}

// y2[c][m] = sum_o y1[c][o] * W2[m][o] + b2[m]
__global__ __launch_bounds__(256) void mlp2(
    const float* __restrict__ y1, const float* __restrict__ W2,
    const float* __restrict__ b2, float* __restrict__ out) {
    __shared__ alignas(16) float row[512];
    int c = blockIdx.x, t = threadIdx.x;
    row[t] = y1[(size_t)c * 512 + t];
    row[t + 256] = y1[(size_t)c * 512 + t + 256];
    __syncthreads();
    float acc = 0.f;
    #pragma unroll 4
    for (int o = 0; o < 512; o += 4) {
        float4 w4 = *(const float4*)(W2 + (size_t)t * 512 + o);
        float4 r4 = *(const float4*)(&row[o]);
        acc += w4.x * r4.x + w4.y * r4.y + w4.z * r4.z + w4.w * r4.w;
    }
    out[(size_t)c * 256 + t] = acc + b2[t];
}

extern "C" void kernel_launch(void* const* d_in, const int* in_sizes, int n_in,
                              void* d_out, int out_size, void* d_ws, size_t ws_size,
                              hipStream_t stream) {
    const float* x   = (const float*)d_in[0];
    const int*   adj = (const int*)d_in[1];
    const float* W   = (const float*)d_in[2];
    const float* a1  = (const float*)d_in[3];
    const float* a2  = (const float*)d_in[4];
    const float* Wo  = (const float*)d_in[5];
    const float* ao1 = (const float*)d_in[6];
    const float* ao2 = (const float*)d_in[7];
    const float* W1  = (const float*)d_in[8];
    const float* b1  = (const float*)d_in[9];
    const float* W2  = (const float*)d_in[10];
    const float* b2  = (const float*)d_in[11];
    float* out = (float*)d_out;

    char* ws = (char*)d_ws;
    size_t off = 0;
    auto alloc = [&](size_t bytes) {
        void* p = ws + off;
        off += (bytes + 255) & ~(size_t)255;
        return p;
    };
    unsigned long long* mb = (unsigned long long*)alloc((size_t)N_NODES * NW * 8);
    float* Wh1    = (float*)alloc((size_t)N_NODES * 512 * 4);
    float* hbuf   = (float*)alloc((size_t)N_NODES * 512 * 4);
    float* Who    = (float*)alloc((size_t)N_NODES * 64 * 4);
    float* attout = (float*)alloc((size_t)N_NODES * 64 * 4);
    float* f1b    = (float*)alloc((size_t)9 * N_NODES * 4);
    float* f2b    = (float*)alloc((size_t)9 * N_NODES * 4);
    float* gmb    = (float*)alloc(16 * 4);
    float* y1     = (float*)alloc((size_t)64 * 512 * 4);
    (void)ws_size; (void)in_sizes; (void)n_in; (void)out_size;

    pack_mask<<<1024, 256, 0, stream>>>(adj, mb);
    // Wh1[i][k*64+d] = sum_f x[i][f] W[k][f][d]
    gemm64<1><<<dim3(8, 64), 256, 0, stream>>>(x, W, Wh1, N_NODES, 512, FIN, FIN, 0, 512);
    f1f2k<<<dim3(1024, NHEAD), 256, 0, stream>>>(Wh1, 512, 64, a1, a2, f1b, f2b);
    gmaxk<<<NHEAD, 256, 0, stream>>>(f2b, gmb);
    // layer-1 attention, writes h = elu(att @ Wh) into hbuf[i][k*64+d]
    attn64<<<dim3(N_NODES / 16, NHEAD), 256, 0, stream>>>(
        Wh1, 512, 64, f1b, f2b, gmb, mb, hbuf, 512, 64);
    // Who = h @ Wo
    gemm64<0><<<dim3(1, 64), 256, 0, stream>>>(hbuf, Wo, Who, N_NODES, 64, 512, 512, 64, 64);
    f1f2k<<<dim3(1024, 1), 256, 0, stream>>>(Who, 64, 0, ao1, ao2,
                                             f1b + (size_t)8 * N_NODES, f2b + (size_t)8 * N_NODES);
    gmaxk<<<1, 256, 0, stream>>>(f2b + (size_t)8 * N_NODES, gmb + 8);
    attn64<<<dim3(N_NODES / 16, 1), 256, 0, stream>>>(
        Who, 64, 0, f1b + (size_t)8 * N_NODES, f2b + (size_t)8 * N_NODES, gmb + 8, mb,
        attout, 64, 0);
    lsm_col<<<64, 256, 0, stream>>>(attout);
    mlp1<<<128, 256, 0, stream>>>(attout, W1, b1, y1);
    mlp2<<<64, 256, 0, stream>>>(y1, W2, b2, out);
}

// Round 2
// 477.693 us; speedup vs baseline: 2.2262x; 2.2262x over previous
//
#include <hip/hip_runtime.h>
#include <hip/hip_bf16.h>
#include <math.h>

// GAT forward. N=4096, Fin=512, H=8, D=64, C=64.
// Round 2: attention PV -> MFMA bf16 (was 744us fp32 VALU loop).
//  1. pack adj -> 64-bit masks
//  2. Wh1 = x @ W (all heads)            fp32 tiled GEMM (MFMA next round)
//  3. transpose Wh -> WhB[h][d][j] bf16  (B-fragment friendly layout)
//  4. f1,f2 per head, gmax = max(f2)
//  5. attention: p-phase fp32 -> bf16 swizzled LDS; PV via mfma_f32_16x16x32_bf16
//  6. layer-2 GAT (same kernels, 1 head), column log_softmax, MLP head

#define N_NODES 4096
#define FIN 512
#define NHEAD 8
#define DHEAD 64
#define NCLS 64
#define NW 64

typedef unsigned short u16;
typedef __attribute__((ext_vector_type(8))) short bf16x8;
typedef __attribute__((ext_vector_type(4))) float f32x4;

__device__ __forceinline__ float lrelu02(float x) { return x > 0.f ? x : 0.2f * x; }
__device__ __forceinline__ u16 bf16u(float x) {
    __hip_bfloat16 h = __float2bfloat16(x);
    return __builtin_bit_cast(unsigned short, h);
}

// ---------------- 1. adjacency -> bitmask ----------------
__global__ void pack_mask(const int* __restrict__ adj, unsigned long long* __restrict__ mb) {
    int nwaves = (gridDim.x * blockDim.x) >> 6;
    int wid = (blockIdx.x * blockDim.x + threadIdx.x) >> 6;
    int lane = threadIdx.x & 63;
    for (int w = wid; w < N_NODES * NW; w += nwaves) {
        int i = w >> 6, wc = w & 63;
        int j = (wc << 6) | lane;
        unsigned long long m = __ballot(adj[(size_t)i * N_NODES + j] > 0);
        if (lane == 0) mb[w] = m;
    }
}

// ---------------- 2. fp32 tiled GEMM, 64x64 tile ----------------
template <int BMODE>
__global__ __launch_bounds__(256) void gemm64(
    const float* __restrict__ A, const float* __restrict__ B, float* __restrict__ C,
    int M, int Ncols, int K, int lda, int ldb, int ldc) {
    __shared__ alignas(16) float As[16][68];
    __shared__ alignas(16) float Bs[16][68];
    int t = threadIdx.x;
    int bn = blockIdx.x * 64;
    int bm = blockIdx.y * 64;
    int tx = t & 15, ty = t >> 4;
    float acc[4][4] = {};
    int ra = t >> 2;
    int ka = (t & 3) * 4;
    int nb = t & 63;
    for (int k0 = 0; k0 < K; k0 += 16) {
        __syncthreads();
        float4 av = *(const float4*)(A + (size_t)(bm + ra) * lda + k0 + ka);
        As[ka + 0][ra] = av.x; As[ka + 1][ra] = av.y;
        As[ka + 2][ra] = av.z; As[ka + 3][ra] = av.w;
        #pragma unroll
        for (int u = 0; u < 4; ++u) {
            int kb = (t >> 6) + u * 4;
            float bv;
            if (BMODE == 1) {
                int col = bn + nb;
                bv = B[(size_t)(col >> 6) * (FIN * DHEAD) + (size_t)(k0 + kb) * DHEAD + (col & 63)];
            } else {
                bv = B[(size_t)(k0 + kb) * ldb + bn + nb];
            }
            Bs[kb][nb] = bv;
        }
        __syncthreads();
        #pragma unroll
        for (int kk = 0; kk < 16; ++kk) {
            float4 a4 = *(const float4*)(&As[kk][ty * 4]);
            float4 b4 = *(const float4*)(&Bs[kk][tx * 4]);
            float aa[4] = {a4.x, a4.y, a4.z, a4.w};
            float bb[4] = {b4.x, b4.y, b4.z, b4.w};
            #pragma unroll
            for (int u = 0; u < 4; ++u)
                #pragma unroll
                for (int v = 0; v < 4; ++v) acc[u][v] = fmaf(aa[u], bb[v], acc[u][v]);
        }
    }
    #pragma unroll
    for (int u = 0; u < 4; ++u)
        #pragma unroll
        for (int v = 0; v < 4; ++v)
            C[(size_t)(bm + ty * 4 + u) * ldc + bn + tx * 4 + v] = acc[u][v];
}

// ---------------- 3. fp32 [N][ld] (64-col slice) -> bf16 transposed [64][N] ----------------
__global__ __launch_bounds__(256) void to_bf16_T(
    const float* __restrict__ src, int ldsrc, int cstep,
    u16* __restrict__ dst, size_t dstep) {
    __shared__ alignas(16) u16 T[64][72];
    const int j0 = blockIdx.x * 64;
    const int c0 = blockIdx.y * cstep;
    u16* d = dst + (size_t)blockIdx.y * dstep;
    const int t = threadIdx.x;
    const int row = t & 63, g = t >> 6;
    #pragma unroll
    for (int k = 0; k < 16; k += 4) {
        float4 v = *(const float4*)(src + (size_t)(j0 + row) * ldsrc + c0 + g * 16 + k);
        T[g * 16 + k + 0][row] = bf16u(v.x);
        T[g * 16 + k + 1][row] = bf16u(v.y);
        T[g * 16 + k + 2][row] = bf16u(v.z);
        T[g * 16 + k + 3][row] = bf16u(v.w);
    }
    __syncthreads();
    const int dd = t >> 2, jc = (t & 3) * 16;
    *(uint4*)(d + (size_t)dd * N_NODES + j0 + jc) = *(const uint4*)&T[dd][jc];
    *(uint4*)(d + (size_t)dd * N_NODES + j0 + jc + 8) = *(const uint4*)&T[dd][jc + 8];
}

// ---------------- 4. f1/f2 per row ----------------
__global__ __launch_bounds__(256) void f1f2k(
    const float* __restrict__ Wh, int ldwh, int whstep,
    const float* __restrict__ a1a, const float* __restrict__ a2a,
    float* __restrict__ f1o, float* __restrict__ f2o) {
    int h = blockIdx.y;
    int wv = threadIdx.x >> 6, lane = threadIdx.x & 63;
    int row = blockIdx.x * 4 + wv;
    const float* a1 = a1a + h * DHEAD;
    const float* a2 = a2a + h * DHEAD;
    float w = Wh[(size_t)row * ldwh + h * whstep + lane];
    float s1 = w * a1[lane];
    float s2 = w * a2[lane];
    #pragma unroll
    for (int off = 32; off; off >>= 1) {
        s1 += __shfl_xor(s1, off, 64);
        s2 += __shfl_xor(s2, off, 64);
    }
    if (lane == 0) {
        f1o[(size_t)h * N_NODES + row] = s1;
        f2o[(size_t)h * N_NODES + row] = s2;
    }
}

__global__ void gmaxk(const float* __restrict__ f2, float* __restrict__ gm) {
    int h = blockIdx.x;
    __shared__ float r[256];
    float m = -1e30f;
    for (int i = threadIdx.x; i < N_NODES; i += 256) m = fmaxf(m, f2[(size_t)h * N_NODES + i]);
    r[threadIdx.x] = m;
    __syncthreads();
    for (int s = 128; s; s >>= 1) {
        if (threadIdx.x < s) r[threadIdx.x] = fmaxf(r[threadIdx.x], r[threadIdx.x + s]);
        __syncthreads();
    }
    if (threadIdx.x == 0) gm[h] = r[0];
}

// ---------------- 5. MFMA attention ----------------
// Block = 256 threads (4 waves), 16 output rows, streams 64-wide j tiles.
// p-phase: thread (lane=col j_local, wv) computes p for rows q*4+wv, writes bf16
// into XOR-swizzled LDS. PV: wave wv computes C[16][16] cols wv*16.. via
// mfma_f32_16x16x32_bf16, B loaded straight from global bf16 WhB[h][d][j].
__global__ __launch_bounds__(256) void attn_mfma(
    const u16* __restrict__ WhB, const float* __restrict__ f1a,
    const float* __restrict__ f2a, const float* __restrict__ gmaxa,
    const unsigned long long* __restrict__ mb,
    float* __restrict__ outp, int ldo, int ostep) {
    __shared__ alignas(16) u16 pS[2][16][64];
    __shared__ float denS[16];
    const int h = blockIdx.y;
    const int t = threadIdx.x;
    const int lane = t & 63;
    const int wv = t >> 6;
    const int i0 = blockIdx.x * 16;
    const float* __restrict__ f1 = f1a + (size_t)h * N_NODES;
    const float* __restrict__ f2 = f2a + (size_t)h * N_NODES;
    const float gmax = gmaxa[h];

    // p-phase constants (rows q*4+wv, col = lane)
    float f1r[4], negM[4];
    int wrow[4], wcol[4];
    #pragma unroll
    for (int q = 0; q < 4; ++q) {
        int row = q * 4 + wv;
        float v = f1[i0 + row];
        f1r[q] = v;
        negM[q] = -lrelu02(v + gmax);
        wrow[q] = row;
        wcol[q] = lane ^ ((row & 7) << 3);  // XOR swizzle (ushort index)
    }
    float den[4] = {0.f, 0.f, 0.f, 0.f};

    // MFMA fragment roles
    const int kgrp = lane >> 4;       // 0..3
    const int c16 = lane & 15;
    const int bcol = wv * 16 + c16;   // output col
    const u16* bptr = WhB + ((size_t)h * DHEAD + bcol) * N_NODES + kgrp * 8;
    const int arow = c16;             // A row
    const int sw8 = (arow & 7) << 3;
    f32x4 acc = {0.f, 0.f, 0.f, 0.f};

    for (int jt = 0; jt < N_NODES / 64; ++jt) {
        // issue B loads early; L2 latency hides under p-phase
        bf16x8 b0 = *(const bf16x8*)(bptr + (size_t)jt * 64);
        bf16x8 b1 = *(const bf16x8*)(bptr + (size_t)jt * 64 + 32);
        float f2v = f2[jt * 64 + lane];
        int buf = jt & 1;
        #pragma unroll
        for (int q = 0; q < 4; ++q) {
            unsigned long long w = mb[(size_t)(i0 + wrow[q]) * NW + jt];  // wave-uniform
            float s = lrelu02(f1r[q] + f2v);
            float p = ((w >> lane) & 1ULL) ? __expf(s + negM[q]) : 0.f;
            den[q] += p;
            pS[buf][wrow[q]][wcol[q]] = bf16u(p);
        }
        __syncthreads();  // pS[buf] ready; also fences prev iter's reads (lgkmcnt drain)
        const u16* ap = &pS[buf][arow][0];
        bf16x8 a0 = *(const bf16x8*)&ap[(kgrp * 8) ^ sw8];
        bf16x8 a1 = *(const bf16x8*)&ap[(32 + kgrp * 8) ^ sw8];
        acc = __builtin_amdgcn_mfma_f32_16x16x32_bf16(a0, b0, acc, 0, 0, 0);
        acc = __builtin_amdgcn_mfma_f32_16x16x32_bf16(a1, b1, acc, 0, 0, 0);
    }

    // full-row denominators: each wave owns rows q*4+wv across all 64 lanes
    #pragma unroll
    for (int q = 0; q < 4; ++q)
        #pragma unroll
        for (int off = 32; off; off >>= 1) den[q] += __shfl_xor(den[q], off, 64);
    if (lane == 0) {
        #pragma unroll
        for (int q = 0; q < 4; ++q) denS[wrow[q]] = den[q];
    }
    __syncthreads();
    // C/D layout: col = lane&15, row = (lane>>4)*4 + reg
    const int oc = h * ostep;
    #pragma unroll
    for (int r = 0; r < 4; ++r) {
        int row = kgrp * 4 + r;
        float dn = denS[row];
        float v = dn > 0.f ? acc[r] / dn : 0.f;
        v = v > 0.f ? v : expm1f(v);  // ELU
        outp[(size_t)(i0 + row) * ldo + oc + bcol] = v;
    }
}

// ---------------- 6. column log_softmax, in place ----------------
__global__ void lsm_col(float* __restrict__ o) {
    int c = blockIdx.x, t = threadIdx.x;
    __shared__ float r[256];
    float m = -1e30f;
    for (int i = t; i < N_NODES; i += 256) m = fmaxf(m, o[(size_t)i * NCLS + c]);
    r[t] = m;
    __syncthreads();
    for (int s = 128; s; s >>= 1) {
        if (t < s) r[t] = fmaxf(r[t], r[t + s]);
        __syncthreads();
    }
    m = r[0];
    __syncthreads();
    float sum = 0.f;
    for (int i = t; i < N_NODES; i += 256) sum += __expf(o[(size_t)i * NCLS + c] - m);
    r[t] = sum;
    __syncthreads();
    for (int s = 128; s; s >>= 1) {
        if (t < s) r[t] += r[t + s];
        __syncthreads();
    }
    float lse = m + __logf(r[0]);
    for (int i = t; i < N_NODES; i += 256) o[(size_t)i * NCLS + c] -= lse;
}

// ---------------- 7. MLP head ----------------
__global__ __launch_bounds__(256) void mlp1(
    const float* __restrict__ ls, const float* __restrict__ W1,
    const float* __restrict__ b1, float* __restrict__ y1) {
    int wv = threadIdx.x >> 6, c = threadIdx.x & 63;
    int o = blockIdx.x * 4 + wv;
    float acc = 0.f;
    for (int i = 0; i < N_NODES; i += 4) {
        float4 w4 = *(const float4*)(W1 + (size_t)o * N_NODES + i);
        acc = fmaf(w4.x, ls[(size_t)(i + 0) * NCLS + c], acc);
        acc = fmaf(w4.y, ls[(size_t)(i + 1) * NCLS + c], acc);
        acc = fmaf(w4.z, ls[(size_t)(i + 2) * NCLS + c], acc);
        acc = fmaf(w4.w, ls[(size_t)(i + 3) * NCLS + c], acc);
    }
    acc += b1[o];
    acc = acc > 0.f ? acc : 0.1f * acc;
    y1[(size_t)c * 512 + o] = acc;
}

__global__ __launch_bounds__(256) void mlp2(
    const float* __restrict__ y1, const float* __restrict__ W2,
    const float* __restrict__ b2, float* __restrict__ out) {
    __shared__ alignas(16) float row[512];
    int c = blockIdx.x, t = threadIdx.x;
    row[t] = y1[(size_t)c * 512 + t];
    row[t + 256] = y1[(size_t)c * 512 + t + 256];
    __syncthreads();
    float acc = 0.f;
    #pragma unroll 4
    for (int o = 0; o < 512; o += 4) {
        float4 w4 = *(const float4*)(W2 + (size_t)t * 512 + o);
        float4 r4 = *(const float4*)(&row[o]);
        acc += w4.x * r4.x + w4.y * r4.y + w4.z * r4.z + w4.w * r4.w;
    }
    out[(size_t)c * 256 + t] = acc + b2[t];
}

extern "C" void kernel_launch(void* const* d_in, const int* in_sizes, int n_in,
                              void* d_out, int out_size, void* d_ws, size_t ws_size,
                              hipStream_t stream) {
    const float* x   = (const float*)d_in[0];
    const int*   adj = (const int*)d_in[1];
    const float* W   = (const float*)d_in[2];
    const float* a1  = (const float*)d_in[3];
    const float* a2  = (const float*)d_in[4];
    const float* Wo  = (const float*)d_in[5];
    const float* ao1 = (const float*)d_in[6];
    const float* ao2 = (const float*)d_in[7];
    const float* W1  = (const float*)d_in[8];
    const float* b1  = (const float*)d_in[9];
    const float* W2  = (const float*)d_in[10];
    const float* b2  = (const float*)d_in[11];
    float* out = (float*)d_out;

    char* ws = (char*)d_ws;
    size_t off = 0;
    auto alloc = [&](size_t bytes) {
        void* p = ws + off;
        off += (bytes + 255) & ~(size_t)255;
        return p;
    };
    unsigned long long* mb = (unsigned long long*)alloc((size_t)N_NODES * NW * 8);
    float* Wh1    = (float*)alloc((size_t)N_NODES * 512 * 4);
    float* hbuf   = (float*)alloc((size_t)N_NODES * 512 * 4);
    float* Who    = (float*)alloc((size_t)N_NODES * 64 * 4);
    float* attout = (float*)alloc((size_t)N_NODES * 64 * 4);
    float* f1b    = (float*)alloc((size_t)9 * N_NODES * 4);
    float* f2b    = (float*)alloc((size_t)9 * N_NODES * 4);
    float* gmb    = (float*)alloc(16 * 4);
    float* y1     = (float*)alloc((size_t)64 * 512 * 4);
    u16*   WhB    = (u16*)alloc((size_t)NHEAD * DHEAD * N_NODES * 2);  // [h][d][j]
    u16*   WhoB   = (u16*)alloc((size_t)DHEAD * N_NODES * 2);          // [d][j]
    (void)ws_size; (void)in_sizes; (void)n_in; (void)out_size;

    pack_mask<<<1024, 256, 0, stream>>>(adj, mb);
    gemm64<1><<<dim3(8, 64), 256, 0, stream>>>(x, W, Wh1, N_NODES, 512, FIN, FIN, 0, 512);
    to_bf16_T<<<dim3(64, NHEAD), 256, 0, stream>>>(Wh1, 512, 64, WhB, (size_t)DHEAD * N_NODES);
    f1f2k<<<dim3(1024, NHEAD), 256, 0, stream>>>(Wh1, 512, 64, a1, a2, f1b, f2b);
    gmaxk<<<NHEAD, 256, 0, stream>>>(f2b, gmb);
    attn_mfma<<<dim3(N_NODES / 16, NHEAD), 256, 0, stream>>>(
        WhB, f1b, f2b, gmb, mb, hbuf, 512, 64);
    gemm64<0><<<dim3(1, 64), 256, 0, stream>>>(hbuf, Wo, Who, N_NODES, 64, 512, 512, 64, 64);
    to_bf16_T<<<dim3(64, 1), 256, 0, stream>>>(Who, 64, 0, WhoB, 0);
    f1f2k<<<dim3(1024, 1), 256, 0, stream>>>(Who, 64, 0, ao1, ao2,
                                             f1b + (size_t)8 * N_NODES, f2b + (size_t)8 * N_NODES);
    gmaxk<<<1, 256, 0, stream>>>(f2b + (size_t)8 * N_NODES, gmb + 8);
    attn_mfma<<<dim3(N_NODES / 16, 1), 256, 0, stream>>>(
        WhoB, f1b + (size_t)8 * N_NODES, f2b + (size_t)8 * N_NODES, gmb + 8, mb,
        attout, 64, 0);
    lsm_col<<<64, 256, 0, stream>>>(attout);
    mlp1<<<128, 256, 0, stream>>>(attout, W1, b1, y1);
    mlp2<<<64, 256, 0, stream>>>(y1, W2, b2, out);
}

// Round 4
// 408.608 us; speedup vs baseline: 2.6026x; 1.1691x over previous
//
#include <hip/hip_runtime.h>
#include <hip/hip_bf16.h>
#include <math.h>

// GAT forward. N=4096, Fin=512, H=8, D=64, C=64.
// Round 4 (= round 3 with the asm mask fixed):
//  - attention p-phase: exp factorized out (p = mask ? (u>thr ? A*u : B*v) : 0).
//    Mask word made PROVABLY uniform (readfirstlane) -> s_load + single
//    v_cndmask_b32 with the adjacency u64 as an SGPR-pair lane mask.
//  - both feature GEMMs (x@W, h@Wo) -> bf16 MFMA, fragments straight from L2.
//  - layer-1 attention writes bf16 h directly (aliases Wh1 buffer).

#define N_NODES 4096
#define FIN 512
#define NHEAD 8
#define DHEAD 64
#define NCLS 64
#define NW 64

typedef unsigned short u16;
typedef unsigned long long u64;
typedef __attribute__((ext_vector_type(8))) short bf16x8;
typedef __attribute__((ext_vector_type(4))) float f32x4;

__device__ __forceinline__ float lrelu02(float x) { return x > 0.f ? x : 0.2f * x; }
__device__ __forceinline__ u16 bf16u(float x) {
    __hip_bfloat16 h = __float2bfloat16(x);
    return __builtin_bit_cast(unsigned short, h);
}
__device__ __forceinline__ f32x4 mfma16(bf16x8 a, bf16x8 b, f32x4 c) {
    return __builtin_amdgcn_mfma_f32_16x16x32_bf16(a, b, c, 0, 0, 0);
}

// ---------------- adjacency -> bitmask ----------------
__global__ void pack_mask(const int* __restrict__ adj, u64* __restrict__ mb) {
    int nwaves = (gridDim.x * blockDim.x) >> 6;
    int wid = (blockIdx.x * blockDim.x + threadIdx.x) >> 6;
    int lane = threadIdx.x & 63;
    for (int w = wid; w < N_NODES * NW; w += nwaves) {
        int i = w >> 6, wc = w & 63;
        int j = (wc << 6) | lane;
        u64 m = __ballot(adj[(size_t)i * N_NODES + j] > 0);
        if (lane == 0) mb[w] = m;
    }
}

// ---------------- fp32 -> bf16 flat convert ----------------
__global__ void cvt4(const float* __restrict__ s, u16* __restrict__ d, int n4) {
    int i = blockIdx.x * blockDim.x + threadIdx.x;
    if (i < n4) {
        float4 v = ((const float4*)s)[i];
        ushort4 o = {bf16u(v.x), bf16u(v.y), bf16u(v.z), bf16u(v.w)};
        ((ushort4*)d)[i] = o;
    }
}

// ---------------- fp32 [rows][ldsrc] (64-col slice) -> bf16 transposed [64][ldd] ----------------
__global__ __launch_bounds__(256) void to_bf16_T(
    const float* __restrict__ src, int ldsrc, size_t cstep,
    u16* __restrict__ dst, size_t dstep, int ldd) {
    __shared__ alignas(16) u16 T[64][72];
    const int j0 = blockIdx.x * 64;
    const size_t c0 = (size_t)blockIdx.y * cstep;
    u16* d = dst + (size_t)blockIdx.y * dstep;
    const int t = threadIdx.x;
    const int row = t & 63, g = t >> 6;
    #pragma unroll
    for (int k = 0; k < 16; k += 4) {
        float4 v = *(const float4*)(src + (size_t)(j0 + row) * ldsrc + c0 + g * 16 + k);
        T[g * 16 + k + 0][row] = bf16u(v.x);
        T[g * 16 + k + 1][row] = bf16u(v.y);
        T[g * 16 + k + 2][row] = bf16u(v.z);
        T[g * 16 + k + 3][row] = bf16u(v.w);
    }
    __syncthreads();
    const int dd = t >> 2, jc = (t & 3) * 16;
    *(uint4*)(d + (size_t)dd * ldd + j0 + jc) = *(const uint4*)&T[dd][jc];
    *(uint4*)(d + (size_t)dd * ldd + j0 + jc + 8) = *(const uint4*)&T[dd][jc + 8];
}

// ---------------- MFMA GEMM: C[M][N] = A[M][K] * Bt[N][K]^T ----------------
__global__ __launch_bounds__(256) void gemm_mfma(
    const u16* __restrict__ A, int lda, const u16* __restrict__ Bt, int ldb,
    float* __restrict__ C, int ldc, int K) {
    const int t = threadIdx.x, lane = t & 63, wv = t >> 6;
    const int c16 = lane & 15, kg = lane >> 4;
    const int bm = blockIdx.y * 64 + wv * 16;
    const int bn = blockIdx.x * 64;
    const u16* Ap = A + (size_t)(bm + c16) * lda + kg * 8;
    const u16* Bp = Bt + (size_t)(bn + c16) * ldb + kg * 8;
    f32x4 acc[4] = {};
    #pragma unroll 4
    for (int k0 = 0; k0 < K; k0 += 32) {
        bf16x8 a = *(const bf16x8*)(Ap + k0);
        #pragma unroll
        for (int ct = 0; ct < 4; ++ct) {
            bf16x8 b = *(const bf16x8*)(Bp + (size_t)ct * 16 * ldb + k0);
            acc[ct] = mfma16(a, b, acc[ct]);
        }
    }
    #pragma unroll
    for (int ct = 0; ct < 4; ++ct)
        #pragma unroll
        for (int r = 0; r < 4; ++r)
            C[(size_t)(bm + kg * 4 + r) * ldc + bn + ct * 16 + c16] = acc[ct][r];
}

// ---------------- f1/f2 per row ----------------
__global__ __launch_bounds__(256) void f1f2k(
    const float* __restrict__ Wh, int ldwh, int whstep,
    const float* __restrict__ a1a, const float* __restrict__ a2a,
    float* __restrict__ f1o, float* __restrict__ f2o) {
    int h = blockIdx.y;
    int wv = threadIdx.x >> 6, lane = threadIdx.x & 63;
    int row = blockIdx.x * 4 + wv;
    const float* a1 = a1a + h * DHEAD;
    const float* a2 = a2a + h * DHEAD;
    float w = Wh[(size_t)row * ldwh + h * whstep + lane];
    float s1 = w * a1[lane];
    float s2 = w * a2[lane];
    #pragma unroll
    for (int off = 32; off; off >>= 1) {
        s1 += __shfl_xor(s1, off, 64);
        s2 += __shfl_xor(s2, off, 64);
    }
    if (lane == 0) {
        f1o[(size_t)h * N_NODES + row] = s1;
        f2o[(size_t)h * N_NODES + row] = s2;
    }
}

__global__ void gmaxk(const float* __restrict__ f2, float* __restrict__ gm) {
    int h = blockIdx.x;
    __shared__ float r[256];
    float m = -1e30f;
    for (int i = threadIdx.x; i < N_NODES; i += 256) m = fmaxf(m, f2[(size_t)h * N_NODES + i]);
    r[threadIdx.x] = m;
    __syncthreads();
    for (int s = 128; s; s >>= 1) {
        if (threadIdx.x < s) r[threadIdx.x] = fmaxf(r[threadIdx.x], r[threadIdx.x + s]);
        __syncthreads();
    }
    if (threadIdx.x == 0) gm[h] = r[0];
}

// ---------------- per-row / per-col softmax coefficients ----------------
// pos (f1+f2>0): p = A_i*u_j ; neg: p = B_i*v_j ; branch: u_j > thr_i.
__global__ void coefk(const float* __restrict__ f1, const float* __restrict__ f2,
                      const float* __restrict__ gm, float4* __restrict__ rowc,
                      float2* __restrict__ uv) {
    int h = blockIdx.y;
    int i = blockIdx.x * 256 + threadIdx.x;
    float g = gm[h];
    float a = f1[(size_t)h * N_NODES + i];
    float s = a + g;
    float M = lrelu02(s);
    rowc[(size_t)h * N_NODES + i] = make_float4(__expf(s - M), __expf(0.2f * s - M),
                                                __expf(-s), 0.f);
    float b = f2[(size_t)h * N_NODES + i] - g;  // <= 0
    uv[(size_t)h * N_NODES + i] = make_float2(__expf(b), __expf(0.2f * b));
}

// ---------------- attention: factorized p-phase + MFMA PV ----------------
template <int NH, int OUTF>
__global__ __launch_bounds__(256) void attn_fac(
    const u16* __restrict__ WhB,        // [NH][64 d][4096 j] bf16
    const float2* __restrict__ uv, const float4* __restrict__ rowc,
    const u64* __restrict__ mb, void* __restrict__ outp, int ldo, int ostep) {
    __shared__ alignas(16) u16 pS[2][16][64];
    __shared__ float denS[16];
    const int b = blockIdx.x;
    const int h = (NH == 8) ? (b & 7) : 0;
    const int i0 = ((NH == 8) ? (b >> 3) : b) * 16;
    const int t = threadIdx.x, lane = t & 63, wv = t >> 6;
    const int wv_u = __builtin_amdgcn_readfirstlane(wv);  // wave-uniform wave id
    const float2* __restrict__ uvp = uv + (size_t)h * N_NODES;
    const float4* __restrict__ rcp = rowc + (size_t)h * N_NODES;

    float Aq[4], Bq[4], thr[4];
    int wrow[4], wcol[4];
    #pragma unroll
    for (int q = 0; q < 4; ++q) {
        int row = q * 4 + wv;
        float4 rc = rcp[i0 + row];
        Aq[q] = rc.x; Bq[q] = rc.y; thr[q] = rc.z;
        wrow[q] = row;
        wcol[q] = lane ^ ((row & 7) << 3);
    }
    float den[4] = {0.f, 0.f, 0.f, 0.f};

    const int kg = lane >> 4, c16 = lane & 15;
    const int bcol = wv * 16 + c16;
    const u16* bptr = WhB + ((size_t)h * DHEAD + bcol) * N_NODES + kg * 8;
    const int sw8 = (c16 & 7) << 3;
    f32x4 acc = {0.f, 0.f, 0.f, 0.f};

    for (int jt = 0; jt < N_NODES / 64; ++jt) {
        bf16x8 b0 = *(const bf16x8*)(bptr + (size_t)jt * 64);
        bf16x8 b1 = *(const bf16x8*)(bptr + (size_t)jt * 64 + 32);
        float2 uvv = uvp[jt * 64 + lane];
        int buf = jt & 1;
        #pragma unroll
        for (int q = 0; q < 4; ++q) {
            // uniform index -> scalar load of the adjacency word
            int idx = (i0 + q * 4 + wv_u) * NW + jt;
            u64 wq = mb[idx];
            // force SGPR residency so the "s" constraint is satisfiable
            unsigned wlo = __builtin_amdgcn_readfirstlane((unsigned)wq);
            unsigned whi = __builtin_amdgcn_readfirstlane((unsigned)(wq >> 32));
            u64 ws = ((u64)whi << 32) | wlo;
            float au = Aq[q] * uvv.x;
            float bv = Bq[q] * uvv.y;
            float tv = uvv.x > thr[q] ? au : bv;
            float p;
            // adjacency word IS the 64-lane mask (bit = lane = column)
            asm("v_cndmask_b32 %0, 0, %1, %2" : "=v"(p) : "v"(tv), "s"(ws));
            den[q] += p;
            pS[buf][wrow[q]][wcol[q]] = bf16u(p);
        }
        __syncthreads();
        const u16* ap = &pS[buf][c16][0];
        bf16x8 a0 = *(const bf16x8*)&ap[(kg * 8) ^ sw8];
        bf16x8 a1 = *(const bf16x8*)&ap[(32 + kg * 8) ^ sw8];
        acc = mfma16(a0, b0, acc);
        acc = mfma16(a1, b1, acc);
    }

    #pragma unroll
    for (int q = 0; q < 4; ++q)
        #pragma unroll
        for (int off = 32; off; off >>= 1) den[q] += __shfl_xor(den[q], off, 64);
    if (lane == 0) {
        #pragma unroll
        for (int q = 0; q < 4; ++q) denS[wrow[q]] = den[q];
    }
    __syncthreads();
    const int oc = h * ostep;
    #pragma unroll
    for (int r = 0; r < 4; ++r) {
        int row = kg * 4 + r;
        float dn = denS[row];
        float v = dn > 0.f ? acc[r] / dn : 0.f;
        v = v > 0.f ? v : expm1f(v);  // ELU
        if (OUTF == 0)
            ((u16*)outp)[(size_t)(i0 + row) * ldo + oc + bcol] = bf16u(v);
        else
            ((float*)outp)[(size_t)(i0 + row) * ldo + oc + bcol] = v;
    }
}

// ---------------- column log_softmax, in place ----------------
__global__ void lsm_col(float* __restrict__ o) {
    int c = blockIdx.x, t = threadIdx.x;
    __shared__ float r[256];
    float m = -1e30f;
    for (int i = t; i < N_NODES; i += 256) m = fmaxf(m, o[(size_t)i * NCLS + c]);
    r[t] = m;
    __syncthreads();
    for (int s = 128; s; s >>= 1) {
        if (t < s) r[t] = fmaxf(r[t], r[t + s]);
        __syncthreads();
    }
    m = r[0];
    __syncthreads();
    float sum = 0.f;
    for (int i = t; i < N_NODES; i += 256) sum += __expf(o[(size_t)i * NCLS + c] - m);
    r[t] = sum;
    __syncthreads();
    for (int s = 128; s; s >>= 1) {
        if (t < s) r[t] += r[t + s];
        __syncthreads();
    }
    float lse = m + __logf(r[0]);
    for (int i = t; i < N_NODES; i += 256) o[(size_t)i * NCLS + c] -= lse;
}

// ---------------- MLP head ----------------
__global__ __launch_bounds__(256) void mlp1(
    const float* __restrict__ ls, const float* __restrict__ W1,
    const float* __restrict__ b1, float* __restrict__ y1) {
    int wv = threadIdx.x >> 6, c = threadIdx.x & 63;
    int o = blockIdx.x * 4 + wv;
    float acc = 0.f;
    for (int i = 0; i < N_NODES; i += 4) {
        float4 w4 = *(const float4*)(W1 + (size_t)o * N_NODES + i);
        acc = fmaf(w4.x, ls[(size_t)(i + 0) * NCLS + c], acc);
        acc = fmaf(w4.y, ls[(size_t)(i + 1) * NCLS + c], acc);
        acc = fmaf(w4.z, ls[(size_t)(i + 2) * NCLS + c], acc);
        acc = fmaf(w4.w, ls[(size_t)(i + 3) * NCLS + c], acc);
    }
    acc += b1[o];
    acc = acc > 0.f ? acc : 0.1f * acc;
    y1[(size_t)c * 512 + o] = acc;
}

__global__ __launch_bounds__(256) void mlp2(
    const float* __restrict__ y1, const float* __restrict__ W2,
    const float* __restrict__ b2, float* __restrict__ out) {
    __shared__ alignas(16) float row[512];
    int c = blockIdx.x, t = threadIdx.x;
    row[t] = y1[(size_t)c * 512 + t];
    row[t + 256] = y1[(size_t)c * 512 + t + 256];
    __syncthreads();
    float acc = 0.f;
    #pragma unroll 4
    for (int o = 0; o < 512; o += 4) {
        float4 w4 = *(const float4*)(W2 + (size_t)t * 512 + o);
        float4 r4 = *(const float4*)(&row[o]);
        acc += w4.x * r4.x + w4.y * r4.y + w4.z * r4.z + w4.w * r4.w;
    }
    out[(size_t)c * 256 + t] = acc + b2[t];
}

extern "C" void kernel_launch(void* const* d_in, const int* in_sizes, int n_in,
                              void* d_out, int out_size, void* d_ws, size_t ws_size,
                              hipStream_t stream) {
    const float* x   = (const float*)d_in[0];
    const int*   adj = (const int*)d_in[1];
    const float* W   = (const float*)d_in[2];
    const float* a1  = (const float*)d_in[3];
    const float* a2  = (const float*)d_in[4];
    const float* Wo  = (const float*)d_in[5];
    const float* ao1 = (const float*)d_in[6];
    const float* ao2 = (const float*)d_in[7];
    const float* W1  = (const float*)d_in[8];
    const float* b1  = (const float*)d_in[9];
    const float* W2  = (const float*)d_in[10];
    const float* b2  = (const float*)d_in[11];
    float* out = (float*)d_out;

    char* ws = (char*)d_ws;
    size_t off = 0;
    auto alloc = [&](size_t bytes) {
        void* p = ws + off;
        off += (bytes + 255) & ~(size_t)255;
        return p;
    };
    u64*   mb     = (u64*)alloc((size_t)N_NODES * NW * 8);
    u16*   xB     = (u16*)alloc((size_t)N_NODES * FIN * 2);
    u16*   WBt    = (u16*)alloc((size_t)NHEAD * DHEAD * FIN * 2);   // [h][d][f]
    float* Wh1    = (float*)alloc((size_t)N_NODES * 512 * 4);
    u16*   WhB    = (u16*)alloc((size_t)NHEAD * DHEAD * N_NODES * 2);  // [h][d][j]
    u16*   WoBt   = (u16*)alloc((size_t)DHEAD * FIN * 2);           // [d][k]
    float* Who    = (float*)alloc((size_t)N_NODES * 64 * 4);
    u16*   WhoB   = (u16*)alloc((size_t)DHEAD * N_NODES * 2);       // [d][j]
    float* attout = (float*)alloc((size_t)N_NODES * 64 * 4);
    float* f1b    = (float*)alloc((size_t)9 * N_NODES * 4);
    float* f2b    = (float*)alloc((size_t)9 * N_NODES * 4);
    float* gmb    = (float*)alloc(16 * 4);
    float4* rowc  = (float4*)alloc((size_t)9 * N_NODES * 16);
    float2* uvb   = (float2*)alloc((size_t)9 * N_NODES * 8);
    float* y1     = (float*)alloc((size_t)64 * 512 * 4);
    u16*   hB     = (u16*)Wh1;  // alias: Wh1 dead after WhB/f1f2 built
    (void)ws_size; (void)in_sizes; (void)n_in; (void)out_size;

    pack_mask<<<1024, 256, 0, stream>>>(adj, mb);
    cvt4<<<(N_NODES * FIN / 4 + 255) / 256, 256, 0, stream>>>(x, xB, N_NODES * FIN / 4);
    to_bf16_T<<<dim3(8, 8), 256, 0, stream>>>(W, 64, (size_t)FIN * DHEAD, WBt,
                                              (size_t)DHEAD * FIN, FIN);
    gemm_mfma<<<dim3(8, 64), 256, 0, stream>>>(xB, FIN, WBt, FIN, Wh1, 512, FIN);
    f1f2k<<<dim3(1024, 8), 256, 0, stream>>>(Wh1, 512, 64, a1, a2, f1b, f2b);
    gmaxk<<<8, 256, 0, stream>>>(f2b, gmb);
    coefk<<<dim3(16, 8), 256, 0, stream>>>(f1b, f2b, gmb, rowc, uvb);
    to_bf16_T<<<dim3(64, 8), 256, 0, stream>>>(Wh1, 512, 64, WhB,
                                               (size_t)DHEAD * N_NODES, N_NODES);
    attn_fac<8, 0><<<N_NODES / 16 * 8, 256, 0, stream>>>(WhB, uvb, rowc, mb, hB, 512, 64);
    to_bf16_T<<<dim3(8, 1), 256, 0, stream>>>(Wo, 64, 0, WoBt, 0, FIN);
    gemm_mfma<<<dim3(1, 64), 256, 0, stream>>>(hB, 512, WoBt, FIN, Who, 64, FIN);
    f1f2k<<<dim3(1024, 1), 256, 0, stream>>>(Who, 64, 0, ao1, ao2,
                                             f1b + (size_t)8 * N_NODES,
                                             f2b + (size_t)8 * N_NODES);
    gmaxk<<<1, 256, 0, stream>>>(f2b + (size_t)8 * N_NODES, gmb + 8);
    coefk<<<dim3(16, 1), 256, 0, stream>>>(f1b + (size_t)8 * N_NODES,
                                           f2b + (size_t)8 * N_NODES, gmb + 8,
                                           rowc + (size_t)8 * N_NODES,
                                           uvb + (size_t)8 * N_NODES);
    to_bf16_T<<<dim3(64, 1), 256, 0, stream>>>(Who, 64, 0, WhoB, 0, N_NODES);
    attn_fac<1, 1><<<N_NODES / 16, 256, 0, stream>>>(
        WhoB, uvb + (size_t)8 * N_NODES, rowc + (size_t)8 * N_NODES, mb, attout, 64, 0);
    lsm_col<<<64, 256, 0, stream>>>(attout);
    mlp1<<<128, 256, 0, stream>>>(attout, W1, b1, y1);
    mlp2<<<64, 256, 0, stream>>>(y1, W2, b2, out);
}

// Round 5
// 363.998 us; speedup vs baseline: 2.9216x; 1.1226x over previous
//
#include <hip/hip_runtime.h>
#include <hip/hip_bf16.h>
#include <math.h>

// GAT forward. N=4096, Fin=512, H=8, D=64, C=64.
// Round 5:
//  - attn: 64-row blocks (4x less L2 B-traffic), p = mask ? max(A*u, B*v) : 0
//    (exact: A*u >= B*v <=> f1+f2 >= 0), 1 barrier/tile w/ double-buffered pS.
//  - gemm_mfma fused epilogue: writes bf16 TRANSPOSED WhB (LDS transpose),
//    per-row f1/f2 (in-register reduce), atomicMax f2-key -> drops 6 kernels
//    and the fp32 Wh1/Who intermediates.

#define N_NODES 4096
#define FIN 512
#define NHEAD 8
#define DHEAD 64
#define NCLS 64
#define NW 64

typedef unsigned short u16;
typedef unsigned long long u64;
typedef __attribute__((ext_vector_type(8))) short bf16x8;
typedef __attribute__((ext_vector_type(4))) float f32x4;

__device__ __forceinline__ float lrelu02(float x) { return x > 0.f ? x : 0.2f * x; }
__device__ __forceinline__ u16 bf16u(float x) {
    __hip_bfloat16 h = __float2bfloat16(x);
    return __builtin_bit_cast(unsigned short, h);
}
__device__ __forceinline__ f32x4 mfma16(bf16x8 a, bf16x8 b, f32x4 c) {
    return __builtin_amdgcn_mfma_f32_16x16x32_bf16(a, b, c, 0, 0, 0);
}
// monotone float<->uint key for atomicMax over signed floats
__device__ __forceinline__ unsigned fkey(float f) {
    unsigned u = __builtin_bit_cast(unsigned, f);
    return (u & 0x80000000u) ? ~u : (u | 0x80000000u);
}
__device__ __forceinline__ float funkey(unsigned k) {
    unsigned u = (k & 0x80000000u) ? (k ^ 0x80000000u) : ~k;
    return __builtin_bit_cast(float, u);
}

// ---------------- adjacency -> bitmask (+ gmax key init) ----------------
__global__ void pack_mask(const int* __restrict__ adj, u64* __restrict__ mb,
                          unsigned* __restrict__ gmk) {
    if (blockIdx.x == 0 && threadIdx.x < 16) gmk[threadIdx.x] = 0u;
    int nwaves = (gridDim.x * blockDim.x) >> 6;
    int wid = (blockIdx.x * blockDim.x + threadIdx.x) >> 6;
    int lane = threadIdx.x & 63;
    for (int w = wid; w < N_NODES * NW; w += nwaves) {
        int i = w >> 6, wc = w & 63;
        int j = (wc << 6) | lane;
        u64 m = __ballot(adj[(size_t)i * N_NODES + j] > 0);
        if (lane == 0) mb[w] = m;
    }
}

// ---------------- fp32 -> bf16 flat convert ----------------
__global__ void cvt4(const float* __restrict__ s, u16* __restrict__ d, int n4) {
    int i = blockIdx.x * blockDim.x + threadIdx.x;
    if (i < n4) {
        float4 v = ((const float4*)s)[i];
        ushort4 o = {bf16u(v.x), bf16u(v.y), bf16u(v.z), bf16u(v.w)};
        ((ushort4*)d)[i] = o;
    }
}

// ---------------- fp32 [rows][ldsrc] (64-col slice) -> bf16 transposed [64][ldd] ----
__global__ __launch_bounds__(256) void to_bf16_T(
    const float* __restrict__ src, int ldsrc, size_t cstep,
    u16* __restrict__ dst, size_t dstep, int ldd) {
    __shared__ alignas(16) u16 T[64][72];
    const int j0 = blockIdx.x * 64;
    const size_t c0 = (size_t)blockIdx.y * cstep;
    u16* d = dst + (size_t)blockIdx.y * dstep;
    const int t = threadIdx.x;
    const int row = t & 63, g = t >> 6;
    #pragma unroll
    for (int k = 0; k < 16; k += 4) {
        float4 v = *(const float4*)(src + (size_t)(j0 + row) * ldsrc + c0 + g * 16 + k);
        T[g * 16 + k + 0][row] = bf16u(v.x);
        T[g * 16 + k + 1][row] = bf16u(v.y);
        T[g * 16 + k + 2][row] = bf16u(v.z);
        T[g * 16 + k + 3][row] = bf16u(v.w);
    }
    __syncthreads();
    const int dd = t >> 2, jc = (t & 3) * 16;
    *(uint4*)(d + (size_t)dd * ldd + j0 + jc) = *(const uint4*)&T[dd][jc];
    *(uint4*)(d + (size_t)dd * ldd + j0 + jc + 8) = *(const uint4*)&T[dd][jc + 8];
}

// ---------------- fused MFMA GEMM ----------------
// C-tile = A[M][K] * Bt[h*64..][K]^T  (64x64 per block), then:
//   - WhBT[h*64+d][4096] bf16 transposed store (LDS transpose)
//   - f1/f2 per row (reduce acc . a1/a2), atomicMax of f2 key
__global__ __launch_bounds__(256) void gemm_fused(
    const u16* __restrict__ A, int lda, const u16* __restrict__ Bt, int ldb,
    const float* __restrict__ a1a, const float* __restrict__ a2a,
    u16* __restrict__ WhBT, float* __restrict__ f1o, float* __restrict__ f2o,
    unsigned* __restrict__ gmk, int K) {
    __shared__ alignas(16) u16 T[64][72];
    const int t = threadIdx.x, lane = t & 63, wv = t >> 6;
    const int c16 = lane & 15, kg = lane >> 4;
    const int h = blockIdx.x;
    const int bm = blockIdx.y * 64;
    const u16* Ap = A + (size_t)(bm + wv * 16 + c16) * lda + kg * 8;
    const u16* Bp = Bt + (size_t)(h * 64 + c16) * ldb + kg * 8;
    f32x4 acc[4] = {};
    #pragma unroll 4
    for (int k0 = 0; k0 < K; k0 += 32) {
        bf16x8 a = *(const bf16x8*)(Ap + k0);
        #pragma unroll
        for (int ct = 0; ct < 4; ++ct) {
            bf16x8 b = *(const bf16x8*)(Bp + (size_t)ct * 16 * ldb + k0);
            acc[ct] = mfma16(a, b, acc[ct]);
        }
    }
    // epilogue: f1/f2 + bf16 transpose staging
    float a1v[4], a2v[4];
    #pragma unroll
    for (int ct = 0; ct < 4; ++ct) {
        a1v[ct] = a1a[h * 64 + ct * 16 + c16];
        a2v[ct] = a2a[h * 64 + ct * 16 + c16];
    }
    float mx = -1e30f;
    #pragma unroll
    for (int r = 0; r < 4; ++r) {
        float s1 = 0.f, s2 = 0.f;
        int rl = wv * 16 + kg * 4 + r;  // row within tile
        #pragma unroll
        for (int ct = 0; ct < 4; ++ct) {
            float v = acc[ct][r];
            s1 = fmaf(v, a1v[ct], s1);
            s2 = fmaf(v, a2v[ct], s2);
            T[ct * 16 + c16][rl] = bf16u(v);
        }
        #pragma unroll
        for (int off = 1; off < 16; off <<= 1) {
            s1 += __shfl_xor(s1, off, 64);
            s2 += __shfl_xor(s2, off, 64);
        }
        if (c16 == 0) {
            f1o[(size_t)h * N_NODES + bm + rl] = s1;
            f2o[(size_t)h * N_NODES + bm + rl] = s2;
        }
        mx = fmaxf(mx, s2);  // s2 is full row-sum on every lane after reduce
    }
    mx = fmaxf(mx, __shfl_xor(mx, 16, 64));
    mx = fmaxf(mx, __shfl_xor(mx, 32, 64));
    if (lane == 0) atomicMax(&gmk[h], fkey(mx));
    __syncthreads();
    const int dd = t >> 2, jc = (t & 3) * 16;
    u16* dst = WhBT + (size_t)(h * 64 + dd) * N_NODES + bm;
    *(uint4*)(dst + jc) = *(const uint4*)&T[dd][jc];
    *(uint4*)(dst + jc + 8) = *(const uint4*)&T[dd][jc + 8];
}

// ---------------- per-row / per-col softmax coefficients ----------------
// p_unmasked(i,j) = max(A_i*u_j, B_i*v_j)  (exact for leaky_relu softmax)
__global__ void coefk(const float* __restrict__ f1, const float* __restrict__ f2,
                      const unsigned* __restrict__ gmk, float4* __restrict__ rowc,
                      float2* __restrict__ uv) {
    int h = blockIdx.y;
    int i = blockIdx.x * 256 + threadIdx.x;
    float g = funkey(gmk[h]);
    float a = f1[(size_t)h * N_NODES + i];
    float s = a + g;
    float M = lrelu02(s);
    rowc[(size_t)h * N_NODES + i] = make_float4(__expf(s - M), __expf(0.2f * s - M), 0.f, 0.f);
    float b = f2[(size_t)h * N_NODES + i] - g;  // <= 0
    uv[(size_t)h * N_NODES + i] = make_float2(__expf(b), __expf(0.2f * b));
}

// ---------------- attention v2: ROWS-row blocks, 1 barrier/tile ----------------
template <int NH, int ROWS, int OUTF>
__global__ __launch_bounds__(256) void attn_v2(
    const u16* __restrict__ WhB,  // [NH*64 d][4096 j]
    const float2* __restrict__ uv, const float4* __restrict__ rowc,
    const u64* __restrict__ mb, void* __restrict__ outp, int ldo, int ostep) {
    constexpr int NQ = ROWS / 4;
    constexpr int NMT = ROWS / 16;
    __shared__ alignas(16) u16 pS[2][ROWS][64];
    __shared__ float denS[ROWS];
    const int b = blockIdx.x;
    const int h = (NH == 8) ? (b & 7) : 0;
    const int i0 = ((NH == 8) ? (b >> 3) : b) * ROWS;
    const int t = threadIdx.x, lane = t & 63, wv = t >> 6;
    const int wv_u = __builtin_amdgcn_readfirstlane(wv);

    const float2* __restrict__ uvp = uv + (size_t)h * N_NODES;
    const float4* __restrict__ rcp = rowc + (size_t)h * N_NODES;
    const u64* __restrict__ mbp = mb + (size_t)(i0 + wv_u) * NW;

    float Aq[NQ], Bq[NQ], den[NQ];
    #pragma unroll
    for (int q = 0; q < NQ; ++q) {
        float4 rc = rcp[i0 + q * 4 + wv];
        Aq[q] = rc.x; Bq[q] = rc.y; den[q] = 0.f;
    }
    // swizzled p columns: (q*4+wv)&7 is wv (q even) or wv+4 (q odd)
    const int wcE = lane ^ (wv << 3);
    const int wcO = lane ^ ((wv + 4) << 3);

    const int kg = lane >> 4, c16 = lane & 15;
    const int ocol = wv * 16 + c16;
    const u16* bptr = WhB + ((size_t)h * 64 + ocol) * N_NODES + kg * 8;
    const int sw8 = (c16 & 7) << 3;
    f32x4 acc[NMT] = {};

    for (int jt = 0; jt < N_NODES / 64; ++jt) {
        bf16x8 b0 = *(const bf16x8*)(bptr + (size_t)jt * 64);
        bf16x8 b1 = *(const bf16x8*)(bptr + (size_t)jt * 64 + 32);
        float2 uvv = uvp[jt * 64 + lane];
        int buf = jt & 1;
        #pragma unroll
        for (int q = 0; q < NQ; ++q) {
            u64 wq = mbp[q * 4 * NW + jt];  // uniform -> s_load
            unsigned wlo = __builtin_amdgcn_readfirstlane((unsigned)wq);
            unsigned whi = __builtin_amdgcn_readfirstlane((unsigned)(wq >> 32));
            u64 ws = ((u64)whi << 32) | wlo;
            float tv = fmaxf(Aq[q] * uvv.x, Bq[q] * uvv.y);
            float p;
            asm("v_cndmask_b32 %0, 0, %1, %2" : "=v"(p) : "v"(tv), "s"(ws));
            den[q] += p;
            pS[buf][q * 4 + wv][(q & 1) ? wcO : wcE] = bf16u(p);
        }
        __syncthreads();  // pS[buf] ready (prev reads drained by waitcnt@barrier)
        #pragma unroll
        for (int mt = 0; mt < NMT; ++mt) {
            const u16* ap = &pS[buf][mt * 16 + c16][0];
            bf16x8 a0 = *(const bf16x8*)&ap[(kg * 8) ^ sw8];
            bf16x8 a1 = *(const bf16x8*)&ap[(32 + kg * 8) ^ sw8];
            acc[mt] = mfma16(a0, b0, acc[mt]);
            acc[mt] = mfma16(a1, b1, acc[mt]);
        }
    }

    #pragma unroll
    for (int q = 0; q < NQ; ++q) {
        float s = den[q];
        #pragma unroll
        for (int off = 32; off; off >>= 1) s += __shfl_xor(s, off, 64);
        if (lane == 0) denS[q * 4 + wv] = s;
    }
    __syncthreads();
    const int oc = h * ostep;
    #pragma unroll
    for (int mt = 0; mt < NMT; ++mt)
        #pragma unroll
        for (int r = 0; r < 4; ++r) {
            int row = mt * 16 + kg * 4 + r;
            float dn = denS[row];
            float v = dn > 0.f ? acc[mt][r] / dn : 0.f;
            v = v > 0.f ? v : expm1f(v);  // ELU
            if (OUTF == 0)
                ((u16*)outp)[(size_t)(i0 + row) * ldo + oc + ocol] = bf16u(v);
            else
                ((float*)outp)[(size_t)(i0 + row) * ldo + oc + ocol] = v;
        }
}

// ---------------- column log_softmax, in place ----------------
__global__ void lsm_col(float* __restrict__ o) {
    int c = blockIdx.x, t = threadIdx.x;
    __shared__ float r[256];
    float m = -1e30f;
    for (int i = t; i < N_NODES; i += 256) m = fmaxf(m, o[(size_t)i * NCLS + c]);
    r[t] = m;
    __syncthreads();
    for (int s = 128; s; s >>= 1) {
        if (t < s) r[t] = fmaxf(r[t], r[t + s]);
        __syncthreads();
    }
    m = r[0];
    __syncthreads();
    float sum = 0.f;
    for (int i = t; i < N_NODES; i += 256) sum += __expf(o[(size_t)i * NCLS + c] - m);
    r[t] = sum;
    __syncthreads();
    for (int s = 128; s; s >>= 1) {
        if (t < s) r[t] += r[t + s];
        __syncthreads();
    }
    float lse = m + __logf(r[0]);
    for (int i = t; i < N_NODES; i += 256) o[(size_t)i * NCLS + c] -= lse;
}

// ---------------- MLP head ----------------
__global__ __launch_bounds__(256) void mlp1(
    const float* __restrict__ ls, const float* __restrict__ W1,
    const float* __restrict__ b1, float* __restrict__ y1) {
    int wv = threadIdx.x >> 6, c = threadIdx.x & 63;
    int o = blockIdx.x * 4 + wv;
    float acc = 0.f;
    for (int i = 0; i < N_NODES; i += 4) {
        float4 w4 = *(const float4*)(W1 + (size_t)o * N_NODES + i);
        acc = fmaf(w4.x, ls[(size_t)(i + 0) * NCLS + c], acc);
        acc = fmaf(w4.y, ls[(size_t)(i + 1) * NCLS + c], acc);
        acc = fmaf(w4.z, ls[(size_t)(i + 2) * NCLS + c], acc);
        acc = fmaf(w4.w, ls[(size_t)(i + 3) * NCLS + c], acc);
    }
    acc += b1[o];
    acc = acc > 0.f ? acc : 0.1f * acc;
    y1[(size_t)c * 512 + o] = acc;
}

__global__ __launch_bounds__(256) void mlp2(
    const float* __restrict__ y1, const float* __restrict__ W2,
    const float* __restrict__ b2, float* __restrict__ out) {
    __shared__ alignas(16) float row[512];
    int c = blockIdx.x, t = threadIdx.x;
    row[t] = y1[(size_t)c * 512 + t];
    row[t + 256] = y1[(size_t)c * 512 + t + 256];
    __syncthreads();
    float acc = 0.f;
    #pragma unroll 4
    for (int o = 0; o < 512; o += 4) {
        float4 w4 = *(const float4*)(W2 + (size_t)t * 512 + o);
        float4 r4 = *(const float4*)(&row[o]);
        acc += w4.x * r4.x + w4.y * r4.y + w4.z * r4.z + w4.w * r4.w;
    }
    out[(size_t)c * 256 + t] = acc + b2[t];
}

extern "C" void kernel_launch(void* const* d_in, const int* in_sizes, int n_in,
                              void* d_out, int out_size, void* d_ws, size_t ws_size,
                              hipStream_t stream) {
    const float* x   = (const float*)d_in[0];
    const int*   adj = (const int*)d_in[1];
    const float* W   = (const float*)d_in[2];
    const float* a1  = (const float*)d_in[3];
    const float* a2  = (const float*)d_in[4];
    const float* Wo  = (const float*)d_in[5];
    const float* ao1 = (const float*)d_in[6];
    const float* ao2 = (const float*)d_in[7];
    const float* W1  = (const float*)d_in[8];
    const float* b1  = (const float*)d_in[9];
    const float* W2  = (const float*)d_in[10];
    const float* b2  = (const float*)d_in[11];
    float* out = (float*)d_out;

    char* ws = (char*)d_ws;
    size_t off = 0;
    auto alloc = [&](size_t bytes) {
        void* p = ws + off;
        off += (bytes + 255) & ~(size_t)255;
        return p;
    };
    u64*     mb     = (u64*)alloc((size_t)N_NODES * NW * 8);
    u16*     xB     = (u16*)alloc((size_t)N_NODES * FIN * 2);
    u16*     WBt    = (u16*)alloc((size_t)NHEAD * DHEAD * FIN * 2);     // [h][d][f]
    u16*     WoBt   = (u16*)alloc((size_t)DHEAD * FIN * 2);             // [d][k]
    u16*     WhB    = (u16*)alloc((size_t)NHEAD * DHEAD * N_NODES * 2); // [h*64+d][j]
    u16*     WhoB   = (u16*)alloc((size_t)DHEAD * N_NODES * 2);         // [d][j]
    u16*     hB     = (u16*)alloc((size_t)N_NODES * 512 * 2);           // elu(att@Wh) bf16
    float*   attout = (float*)alloc((size_t)N_NODES * 64 * 4);
    float*   f1b    = (float*)alloc((size_t)9 * N_NODES * 4);
    float*   f2b    = (float*)alloc((size_t)9 * N_NODES * 4);
    unsigned* gmk   = (unsigned*)alloc(16 * 4);
    float4*  rowc   = (float4*)alloc((size_t)9 * N_NODES * 16);
    float2*  uvb    = (float2*)alloc((size_t)9 * N_NODES * 8);
    float*   y1     = (float*)alloc((size_t)64 * 512 * 4);
    (void)ws_size; (void)in_sizes; (void)n_in; (void)out_size;

    pack_mask<<<1024, 256, 0, stream>>>(adj, mb, gmk);
    cvt4<<<(N_NODES * FIN / 4 + 255) / 256, 256, 0, stream>>>(x, xB, N_NODES * FIN / 4);
    to_bf16_T<<<dim3(8, 8), 256, 0, stream>>>(W, 64, (size_t)FIN * DHEAD, WBt,
                                              (size_t)DHEAD * FIN, FIN);
    to_bf16_T<<<dim3(8, 1), 256, 0, stream>>>(Wo, 64, 0, WoBt, 0, FIN);
    // layer 1: Wh = x@W -> WhB(T) + f1/f2 + gmax
    gemm_fused<<<dim3(8, 64), 256, 0, stream>>>(xB, FIN, WBt, FIN, a1, a2,
                                                WhB, f1b, f2b, gmk, FIN);
    coefk<<<dim3(16, 8), 256, 0, stream>>>(f1b, f2b, gmk, rowc, uvb);
    attn_v2<8, 64, 0><<<(N_NODES / 64) * 8, 256, 0, stream>>>(
        WhB, uvb, rowc, mb, hB, 512, 64);
    // layer 2: Who = h@Wo -> WhoB(T) + f1/f2 + gmax
    gemm_fused<<<dim3(1, 64), 256, 0, stream>>>(hB, 512, WoBt, FIN, ao1, ao2,
                                                WhoB, f1b + (size_t)8 * N_NODES,
                                                f2b + (size_t)8 * N_NODES, gmk + 8, FIN);
    coefk<<<dim3(16, 1), 256, 0, stream>>>(f1b + (size_t)8 * N_NODES,
                                           f2b + (size_t)8 * N_NODES, gmk + 8,
                                           rowc + (size_t)8 * N_NODES,
                                           uvb + (size_t)8 * N_NODES);
    attn_v2<1, 32, 1><<<N_NODES / 32, 256, 0, stream>>>(
        WhoB, uvb + (size_t)8 * N_NODES, rowc + (size_t)8 * N_NODES, mb, attout, 64, 0);
    lsm_col<<<64, 256, 0, stream>>>(attout);
    mlp1<<<128, 256, 0, stream>>>(attout, W1, b1, y1);
    mlp2<<<64, 256, 0, stream>>>(y1, W2, b2, out);
}

// Round 6
// 265.375 us; speedup vs baseline: 4.0074x; 1.3716x over previous
//
#include <hip/hip_runtime.h>
#include <hip/hip_bf16.h>
#include <math.h>

// GAT forward. N=4096, Fin=512, H=8, D=64, C=64.
// Round 6:
//  - mlp1 (was 134us, 4% occupancy) -> split-K bf16 MFMA (8 o-tiles x 16 K-splits)
//    + tiny reduce. W1 row-major IS the Bt fragment layout; only needs bf16 cvt.
//  - layer-2 attention writes TRANSPOSED fp32 attoutT via LDS transpose;
//    log_softmax becomes row-contiguous and emits bf16 lsT for the MFMA A side.

#define N_NODES 4096
#define FIN 512
#define NHEAD 8
#define DHEAD 64
#define NCLS 64
#define NW 64

typedef unsigned short u16;
typedef unsigned long long u64;
typedef __attribute__((ext_vector_type(8))) short bf16x8;
typedef __attribute__((ext_vector_type(4))) float f32x4;

__device__ __forceinline__ float lrelu02(float x) { return x > 0.f ? x : 0.2f * x; }
__device__ __forceinline__ u16 bf16u(float x) {
    __hip_bfloat16 h = __float2bfloat16(x);
    return __builtin_bit_cast(unsigned short, h);
}
__device__ __forceinline__ f32x4 mfma16(bf16x8 a, bf16x8 b, f32x4 c) {
    return __builtin_amdgcn_mfma_f32_16x16x32_bf16(a, b, c, 0, 0, 0);
}
__device__ __forceinline__ unsigned fkey(float f) {
    unsigned u = __builtin_bit_cast(unsigned, f);
    return (u & 0x80000000u) ? ~u : (u | 0x80000000u);
}
__device__ __forceinline__ float funkey(unsigned k) {
    unsigned u = (k & 0x80000000u) ? (k ^ 0x80000000u) : ~k;
    return __builtin_bit_cast(float, u);
}

// ---------------- adjacency -> bitmask (+ gmax key init) ----------------
__global__ void pack_mask(const int* __restrict__ adj, u64* __restrict__ mb,
                          unsigned* __restrict__ gmk) {
    if (blockIdx.x == 0 && threadIdx.x < 16) gmk[threadIdx.x] = 0u;
    int nwaves = (gridDim.x * blockDim.x) >> 6;
    int wid = (blockIdx.x * blockDim.x + threadIdx.x) >> 6;
    int lane = threadIdx.x & 63;
    for (int w = wid; w < N_NODES * NW; w += nwaves) {
        int i = w >> 6, wc = w & 63;
        int j = (wc << 6) | lane;
        u64 m = __ballot(adj[(size_t)i * N_NODES + j] > 0);
        if (lane == 0) mb[w] = m;
    }
}

// ---------------- fp32 -> bf16 flat convert ----------------
__global__ void cvt4(const float* __restrict__ s, u16* __restrict__ d, int n4) {
    int i = blockIdx.x * blockDim.x + threadIdx.x;
    if (i < n4) {
        float4 v = ((const float4*)s)[i];
        ushort4 o = {bf16u(v.x), bf16u(v.y), bf16u(v.z), bf16u(v.w)};
        ((ushort4*)d)[i] = o;
    }
}

// ---------------- fp32 [rows][ldsrc] (64-col slice) -> bf16 transposed [64][ldd] ----
__global__ __launch_bounds__(256) void to_bf16_T(
    const float* __restrict__ src, int ldsrc, size_t cstep,
    u16* __restrict__ dst, size_t dstep, int ldd) {
    __shared__ alignas(16) u16 T[64][72];
    const int j0 = blockIdx.x * 64;
    const size_t c0 = (size_t)blockIdx.y * cstep;
    u16* d = dst + (size_t)blockIdx.y * dstep;
    const int t = threadIdx.x;
    const int row = t & 63, g = t >> 6;
    #pragma unroll
    for (int k = 0; k < 16; k += 4) {
        float4 v = *(const float4*)(src + (size_t)(j0 + row) * ldsrc + c0 + g * 16 + k);
        T[g * 16 + k + 0][row] = bf16u(v.x);
        T[g * 16 + k + 1][row] = bf16u(v.y);
        T[g * 16 + k + 2][row] = bf16u(v.z);
        T[g * 16 + k + 3][row] = bf16u(v.w);
    }
    __syncthreads();
    const int dd = t >> 2, jc = (t & 3) * 16;
    *(uint4*)(d + (size_t)dd * ldd + j0 + jc) = *(const uint4*)&T[dd][jc];
    *(uint4*)(d + (size_t)dd * ldd + j0 + jc + 8) = *(const uint4*)&T[dd][jc + 8];
}

// ---------------- fused MFMA GEMM (x@W / h@Wo + f1/f2 + gmax + bf16-T out) ----
__global__ __launch_bounds__(256) void gemm_fused(
    const u16* __restrict__ A, int lda, const u16* __restrict__ Bt, int ldb,
    const float* __restrict__ a1a, const float* __restrict__ a2a,
    u16* __restrict__ WhBT, float* __restrict__ f1o, float* __restrict__ f2o,
    unsigned* __restrict__ gmk, int K) {
    __shared__ alignas(16) u16 T[64][72];
    const int t = threadIdx.x, lane = t & 63, wv = t >> 6;
    const int c16 = lane & 15, kg = lane >> 4;
    const int h = blockIdx.x;
    const int bm = blockIdx.y * 64;
    const u16* Ap = A + (size_t)(bm + wv * 16 + c16) * lda + kg * 8;
    const u16* Bp = Bt + (size_t)(h * 64 + c16) * ldb + kg * 8;
    f32x4 acc[4] = {};
    #pragma unroll 4
    for (int k0 = 0; k0 < K; k0 += 32) {
        bf16x8 a = *(const bf16x8*)(Ap + k0);
        #pragma unroll
        for (int ct = 0; ct < 4; ++ct) {
            bf16x8 b = *(const bf16x8*)(Bp + (size_t)ct * 16 * ldb + k0);
            acc[ct] = mfma16(a, b, acc[ct]);
        }
    }
    float a1v[4], a2v[4];
    #pragma unroll
    for (int ct = 0; ct < 4; ++ct) {
        a1v[ct] = a1a[h * 64 + ct * 16 + c16];
        a2v[ct] = a2a[h * 64 + ct * 16 + c16];
    }
    float mx = -1e30f;
    #pragma unroll
    for (int r = 0; r < 4; ++r) {
        float s1 = 0.f, s2 = 0.f;
        int rl = wv * 16 + kg * 4 + r;
        #pragma unroll
        for (int ct = 0; ct < 4; ++ct) {
            float v = acc[ct][r];
            s1 = fmaf(v, a1v[ct], s1);
            s2 = fmaf(v, a2v[ct], s2);
            T[ct * 16 + c16][rl] = bf16u(v);
        }
        #pragma unroll
        for (int off = 1; off < 16; off <<= 1) {
            s1 += __shfl_xor(s1, off, 64);
            s2 += __shfl_xor(s2, off, 64);
        }
        if (c16 == 0) {
            f1o[(size_t)h * N_NODES + bm + rl] = s1;
            f2o[(size_t)h * N_NODES + bm + rl] = s2;
        }
        mx = fmaxf(mx, s2);
    }
    mx = fmaxf(mx, __shfl_xor(mx, 16, 64));
    mx = fmaxf(mx, __shfl_xor(mx, 32, 64));
    if (lane == 0) atomicMax(&gmk[h], fkey(mx));
    __syncthreads();
    const int dd = t >> 2, jc = (t & 3) * 16;
    u16* dst = WhBT + (size_t)(h * 64 + dd) * N_NODES + bm;
    *(uint4*)(dst + jc) = *(const uint4*)&T[dd][jc];
    *(uint4*)(dst + jc + 8) = *(const uint4*)&T[dd][jc + 8];
}

// ---------------- per-row / per-col softmax coefficients ----------------
__global__ void coefk(const float* __restrict__ f1, const float* __restrict__ f2,
                      const unsigned* __restrict__ gmk, float4* __restrict__ rowc,
                      float2* __restrict__ uv) {
    int h = blockIdx.y;
    int i = blockIdx.x * 256 + threadIdx.x;
    float g = funkey(gmk[h]);
    float a = f1[(size_t)h * N_NODES + i];
    float s = a + g;
    float M = lrelu02(s);
    rowc[(size_t)h * N_NODES + i] = make_float4(__expf(s - M), __expf(0.2f * s - M), 0.f, 0.f);
    float b = f2[(size_t)h * N_NODES + i] - g;
    uv[(size_t)h * N_NODES + i] = make_float2(__expf(b), __expf(0.2f * b));
}

// ---------------- attention v2 ----------------
// OUTF: 0 -> bf16 row-major; 1 -> fp32 row-major; 2 -> fp32 TRANSPOSED [64][4096]
template <int NH, int ROWS, int OUTF>
__global__ __launch_bounds__(256) void attn_v2(
    const u16* __restrict__ WhB,
    const float2* __restrict__ uv, const float4* __restrict__ rowc,
    const u64* __restrict__ mb, void* __restrict__ outp, int ldo, int ostep) {
    constexpr int NQ = ROWS / 4;
    constexpr int NMT = ROWS / 16;
    __shared__ alignas(16) u16 pS[2][ROWS][64];
    __shared__ float denS[ROWS];
    __shared__ float Tof[(OUTF == 2) ? 64 * 33 : 1];
    const int b = blockIdx.x;
    const int h = (NH == 8) ? (b & 7) : 0;
    const int i0 = ((NH == 8) ? (b >> 3) : b) * ROWS;
    const int t = threadIdx.x, lane = t & 63, wv = t >> 6;
    const int wv_u = __builtin_amdgcn_readfirstlane(wv);

    const float2* __restrict__ uvp = uv + (size_t)h * N_NODES;
    const float4* __restrict__ rcp = rowc + (size_t)h * N_NODES;
    const u64* __restrict__ mbp = mb + (size_t)(i0 + wv_u) * NW;

    float Aq[NQ], Bq[NQ], den[NQ];
    #pragma unroll
    for (int q = 0; q < NQ; ++q) {
        float4 rc = rcp[i0 + q * 4 + wv];
        Aq[q] = rc.x; Bq[q] = rc.y; den[q] = 0.f;
    }
    const int wcE = lane ^ (wv << 3);
    const int wcO = lane ^ ((wv + 4) << 3);

    const int kg = lane >> 4, c16 = lane & 15;
    const int ocol = wv * 16 + c16;
    const u16* bptr = WhB + ((size_t)h * 64 + ocol) * N_NODES + kg * 8;
    const int sw8 = (c16 & 7) << 3;
    f32x4 acc[NMT] = {};

    for (int jt = 0; jt < N_NODES / 64; ++jt) {
        bf16x8 b0 = *(const bf16x8*)(bptr + (size_t)jt * 64);
        bf16x8 b1 = *(const bf16x8*)(bptr + (size_t)jt * 64 + 32);
        float2 uvv = uvp[jt * 64 + lane];
        int buf = jt & 1;
        #pragma unroll
        for (int q = 0; q < NQ; ++q) {
            u64 wq = mbp[q * 4 * NW + jt];
            unsigned wlo = __builtin_amdgcn_readfirstlane((unsigned)wq);
            unsigned whi = __builtin_amdgcn_readfirstlane((unsigned)(wq >> 32));
            u64 ws = ((u64)whi << 32) | wlo;
            float tv = fmaxf(Aq[q] * uvv.x, Bq[q] * uvv.y);
            float p;
            asm("v_cndmask_b32 %0, 0, %1, %2" : "=v"(p) : "v"(tv), "s"(ws));
            den[q] += p;
            pS[buf][q * 4 + wv][(q & 1) ? wcO : wcE] = bf16u(p);
        }
        __syncthreads();
        #pragma unroll
        for (int mt = 0; mt < NMT; ++mt) {
            const u16* ap = &pS[buf][mt * 16 + c16][0];
            bf16x8 a0 = *(const bf16x8*)&ap[(kg * 8) ^ sw8];
            bf16x8 a1 = *(const bf16x8*)&ap[(32 + kg * 8) ^ sw8];
            acc[mt] = mfma16(a0, b0, acc[mt]);
            acc[mt] = mfma16(a1, b1, acc[mt]);
        }
    }

    #pragma unroll
    for (int q = 0; q < NQ; ++q) {
        float s = den[q];
        #pragma unroll
        for (int off = 32; off; off >>= 1) s += __shfl_xor(s, off, 64);
        if (lane == 0) denS[q * 4 + wv] = s;
    }
    __syncthreads();
    if constexpr (OUTF == 2) {
        #pragma unroll
        for (int mt = 0; mt < NMT; ++mt)
            #pragma unroll
            for (int r = 0; r < 4; ++r) {
                int row = mt * 16 + kg * 4 + r;
                float dn = denS[row];
                float v = dn > 0.f ? acc[mt][r] / dn : 0.f;
                v = v > 0.f ? v : expm1f(v);
                Tof[ocol * 33 + row] = v;
            }
        __syncthreads();
        float* oT = (float*)outp;
        int c = t >> 2, r0 = (t & 3) * 8;
        float4 v0 = {Tof[c * 33 + r0 + 0], Tof[c * 33 + r0 + 1],
                     Tof[c * 33 + r0 + 2], Tof[c * 33 + r0 + 3]};
        float4 v1 = {Tof[c * 33 + r0 + 4], Tof[c * 33 + r0 + 5],
                     Tof[c * 33 + r0 + 6], Tof[c * 33 + r0 + 7]};
        *(float4*)(oT + (size_t)c * N_NODES + i0 + r0) = v0;
        *(float4*)(oT + (size_t)c * N_NODES + i0 + r0 + 4) = v1;
    } else {
        const int oc = h * ostep;
        #pragma unroll
        for (int mt = 0; mt < NMT; ++mt)
            #pragma unroll
            for (int r = 0; r < 4; ++r) {
                int row = mt * 16 + kg * 4 + r;
                float dn = denS[row];
                float v = dn > 0.f ? acc[mt][r] / dn : 0.f;
                v = v > 0.f ? v : expm1f(v);
                if (OUTF == 0)
                    ((u16*)outp)[(size_t)(i0 + row) * ldo + oc + ocol] = bf16u(v);
                else
                    ((float*)outp)[(size_t)(i0 + row) * ldo + oc + ocol] = v;
            }
    }
}

// ---------------- row log_softmax on attoutT, emit bf16 lsT ----------------
__global__ __launch_bounds__(256) void lsm_row(const float* __restrict__ aT,
                                               u16* __restrict__ lsT) {
    int c = blockIdx.x, t = threadIdx.x;
    const float* row = aT + (size_t)c * N_NODES;
    __shared__ float r[256];
    float m = -1e30f;
    for (int i = t * 4; i < N_NODES; i += 1024) {
        float4 v = *(const float4*)(row + i);
        m = fmaxf(fmaxf(fmaxf(m, v.x), fmaxf(v.y, v.z)), v.w);
    }
    r[t] = m;
    __syncthreads();
    for (int s = 128; s; s >>= 1) {
        if (t < s) r[t] = fmaxf(r[t], r[t + s]);
        __syncthreads();
    }
    m = r[0];
    __syncthreads();
    float sum = 0.f;
    for (int i = t * 4; i < N_NODES; i += 1024) {
        float4 v = *(const float4*)(row + i);
        sum += __expf(v.x - m) + __expf(v.y - m) + __expf(v.z - m) + __expf(v.w - m);
    }
    r[t] = sum;
    __syncthreads();
    for (int s = 128; s; s >>= 1) {
        if (t < s) r[t] += r[t + s];
        __syncthreads();
    }
    float lse = m + __logf(r[0]);
    for (int i = t * 4; i < N_NODES; i += 1024) {
        float4 v = *(const float4*)(row + i);
        ushort4 o = {bf16u(v.x - lse), bf16u(v.y - lse), bf16u(v.z - lse), bf16u(v.w - lse)};
        *(ushort4*)(lsT + (size_t)c * N_NODES + i) = o;
    }
}

// ---------------- mlp1: split-K MFMA  part[ks][64 c][512 o] ----------------
__global__ __launch_bounds__(256) void mlp1_mfma(
    const u16* __restrict__ lsT,   // [64][4096] bf16
    const u16* __restrict__ W1B,   // [512][4096] bf16 (row-major = Bt layout)
    float* __restrict__ part) {
    const int t = threadIdx.x, lane = t & 63, wv = t >> 6;
    const int c16 = lane & 15, kg = lane >> 4;
    const int ks = blockIdx.x & 15;
    const int bn = (blockIdx.x >> 4) * 64;
    const int kb = ks * 256;
    const u16* Ap = lsT + (size_t)(wv * 16 + c16) * N_NODES + kb + kg * 8;
    const u16* Bp = W1B + (size_t)(bn + c16) * N_NODES + kb + kg * 8;
    f32x4 acc[4] = {};
    #pragma unroll
    for (int k0 = 0; k0 < 256; k0 += 32) {
        bf16x8 a = *(const bf16x8*)(Ap + k0);
        #pragma unroll
        for (int ct = 0; ct < 4; ++ct) {
            bf16x8 b = *(const bf16x8*)(Bp + (size_t)ct * 16 * N_NODES + k0);
            acc[ct] = mfma16(a, b, acc[ct]);
        }
    }
    float* dst = part + (size_t)ks * 64 * 512;
    #pragma unroll
    for (int ct = 0; ct < 4; ++ct)
        #pragma unroll
        for (int r = 0; r < 4; ++r)
            dst[(size_t)(wv * 16 + kg * 4 + r) * 512 + bn + ct * 16 + c16] = acc[ct][r];
}

__global__ void mlp1_fin(const float* __restrict__ part, const float* __restrict__ b1,
                         float* __restrict__ y1) {
    int idx = blockIdx.x * 256 + threadIdx.x;  // 64*512
    int o = idx & 511;
    float s = 0.f;
    #pragma unroll
    for (int ks = 0; ks < 16; ++ks) s += part[(size_t)ks * 32768 + idx];
    s += b1[o];
    y1[idx] = s > 0.f ? s : 0.1f * s;
}

// ---------------- mlp2 ----------------
__global__ __launch_bounds__(256) void mlp2(
    const float* __restrict__ y1, const float* __restrict__ W2,
    const float* __restrict__ b2, float* __restrict__ out) {
    __shared__ alignas(16) float row[512];
    int c = blockIdx.x, t = threadIdx.x;
    row[t] = y1[(size_t)c * 512 + t];
    row[t + 256] = y1[(size_t)c * 512 + t + 256];
    __syncthreads();
    float acc = 0.f;
    #pragma unroll 4
    for (int o = 0; o < 512; o += 4) {
        float4 w4 = *(const float4*)(W2 + (size_t)t * 512 + o);
        float4 r4 = *(const float4*)(&row[o]);
        acc += w4.x * r4.x + w4.y * r4.y + w4.z * r4.z + w4.w * r4.w;
    }
    out[(size_t)c * 256 + t] = acc + b2[t];
}

extern "C" void kernel_launch(void* const* d_in, const int* in_sizes, int n_in,
                              void* d_out, int out_size, void* d_ws, size_t ws_size,
                              hipStream_t stream) {
    const float* x   = (const float*)d_in[0];
    const int*   adj = (const int*)d_in[1];
    const float* W   = (const float*)d_in[2];
    const float* a1  = (const float*)d_in[3];
    const float* a2  = (const float*)d_in[4];
    const float* Wo  = (const float*)d_in[5];
    const float* ao1 = (const float*)d_in[6];
    const float* ao2 = (const float*)d_in[7];
    const float* W1  = (const float*)d_in[8];
    const float* b1  = (const float*)d_in[9];
    const float* W2  = (const float*)d_in[10];
    const float* b2  = (const float*)d_in[11];
    float* out = (float*)d_out;

    char* ws = (char*)d_ws;
    size_t off = 0;
    auto alloc = [&](size_t bytes) {
        void* p = ws + off;
        off += (bytes + 255) & ~(size_t)255;
        return p;
    };
    u64*     mb     = (u64*)alloc((size_t)N_NODES * NW * 8);
    u16*     xB     = (u16*)alloc((size_t)N_NODES * FIN * 2);
    u16*     WBt    = (u16*)alloc((size_t)NHEAD * DHEAD * FIN * 2);
    u16*     WoBt   = (u16*)alloc((size_t)DHEAD * FIN * 2);
    u16*     W1B    = (u16*)alloc((size_t)512 * N_NODES * 2);
    u16*     WhB    = (u16*)alloc((size_t)NHEAD * DHEAD * N_NODES * 2);
    u16*     WhoB   = (u16*)alloc((size_t)DHEAD * N_NODES * 2);
    u16*     hB     = (u16*)alloc((size_t)N_NODES * 512 * 2);
    float*   attoutT= (float*)alloc((size_t)64 * N_NODES * 4);
    u16*     lsT    = (u16*)alloc((size_t)64 * N_NODES * 2);
    float*   part   = (float*)alloc((size_t)16 * 64 * 512 * 4);
    float*   f1b    = (float*)alloc((size_t)9 * N_NODES * 4);
    float*   f2b    = (float*)alloc((size_t)9 * N_NODES * 4);
    unsigned* gmk   = (unsigned*)alloc(16 * 4);
    float4*  rowc   = (float4*)alloc((size_t)9 * N_NODES * 16);
    float2*  uvb    = (float2*)alloc((size_t)9 * N_NODES * 8);
    float*   y1     = (float*)alloc((size_t)64 * 512 * 4);
    (void)ws_size; (void)in_sizes; (void)n_in; (void)out_size;

    pack_mask<<<1024, 256, 0, stream>>>(adj, mb, gmk);
    cvt4<<<(N_NODES * FIN / 4 + 255) / 256, 256, 0, stream>>>(x, xB, N_NODES * FIN / 4);
    cvt4<<<(512 * N_NODES / 4 + 255) / 256, 256, 0, stream>>>(W1, W1B, 512 * N_NODES / 4);
    to_bf16_T<<<dim3(8, 8), 256, 0, stream>>>(W, 64, (size_t)FIN * DHEAD, WBt,
                                              (size_t)DHEAD * FIN, FIN);
    to_bf16_T<<<dim3(8, 1), 256, 0, stream>>>(Wo, 64, 0, WoBt, 0, FIN);
    // layer 1
    gemm_fused<<<dim3(8, 64), 256, 0, stream>>>(xB, FIN, WBt, FIN, a1, a2,
                                                WhB, f1b, f2b, gmk, FIN);
    coefk<<<dim3(16, 8), 256, 0, stream>>>(f1b, f2b, gmk, rowc, uvb);
    attn_v2<8, 64, 0><<<(N_NODES / 64) * 8, 256, 0, stream>>>(
        WhB, uvb, rowc, mb, hB, 512, 64);
    // layer 2
    gemm_fused<<<dim3(1, 64), 256, 0, stream>>>(hB, 512, WoBt, FIN, ao1, ao2,
                                                WhoB, f1b + (size_t)8 * N_NODES,
                                                f2b + (size_t)8 * N_NODES, gmk + 8, FIN);
    coefk<<<dim3(16, 1), 256, 0, stream>>>(f1b + (size_t)8 * N_NODES,
                                           f2b + (size_t)8 * N_NODES, gmk + 8,
                                           rowc + (size_t)8 * N_NODES,
                                           uvb + (size_t)8 * N_NODES);
    attn_v2<1, 32, 2><<<N_NODES / 32, 256, 0, stream>>>(
        WhoB, uvb + (size_t)8 * N_NODES, rowc + (size_t)8 * N_NODES, mb, attoutT,
        N_NODES, 0);
    // log_softmax (rows of attoutT) -> bf16 lsT
    lsm_row<<<64, 256, 0, stream>>>(attoutT, lsT);
    // MLP head
    mlp1_mfma<<<128, 256, 0, stream>>>(lsT, W1B, part);
    mlp1_fin<<<128, 256, 0, stream>>>(part, b1, y1);
    mlp2<<<64, 256, 0, stream>>>(y1, W2, b2, out);
}

// Round 7
// 209.249 us; speedup vs baseline: 5.0823x; 1.2682x over previous
//
#include <hip/hip_runtime.h>
#include <hip/hip_bf16.h>
#include <math.h>

// GAT forward. N=4096, Fin=512, H=8, D=64, C=64.
// Round 7:
//  - attn_v3: register prefetch of uv/masks/B one tile ahead (latency was fully
//    exposed at 2 blocks/CU), setprio around MFMA, j-split grids (attn8 2-way ->
//    1024 blocks, attn1 4-way -> 512 blocks) writing fp32 partials.
//  - combine8: merge attn8 partials -> bf16 hB (elementwise).
//  - combine1_lsm: merge attn1 partials + ELU + column log_softmax fused,
//    emits bf16 lsT directly (replaces lsm_row, drops attoutT).

#define N_NODES 4096
#define FIN 512
#define NHEAD 8
#define DHEAD 64
#define NCLS 64
#define NW 64

typedef unsigned short u16;
typedef unsigned long long u64;
typedef __attribute__((ext_vector_type(8))) short bf16x8;
typedef __attribute__((ext_vector_type(4))) float f32x4;

__device__ __forceinline__ float lrelu02(float x) { return x > 0.f ? x : 0.2f * x; }
__device__ __forceinline__ u16 bf16u(float x) {
    __hip_bfloat16 h = __float2bfloat16(x);
    return __builtin_bit_cast(unsigned short, h);
}
__device__ __forceinline__ f32x4 mfma16(bf16x8 a, bf16x8 b, f32x4 c) {
    return __builtin_amdgcn_mfma_f32_16x16x32_bf16(a, b, c, 0, 0, 0);
}
__device__ __forceinline__ unsigned fkey(float f) {
    unsigned u = __builtin_bit_cast(unsigned, f);
    return (u & 0x80000000u) ? ~u : (u | 0x80000000u);
}
__device__ __forceinline__ float funkey(unsigned k) {
    unsigned u = (k & 0x80000000u) ? (k ^ 0x80000000u) : ~k;
    return __builtin_bit_cast(float, u);
}

// ---------------- adjacency -> bitmask (+ gmax key init) ----------------
__global__ void pack_mask(const int* __restrict__ adj, u64* __restrict__ mb,
                          unsigned* __restrict__ gmk) {
    if (blockIdx.x == 0 && threadIdx.x < 16) gmk[threadIdx.x] = 0u;
    int nwaves = (gridDim.x * blockDim.x) >> 6;
    int wid = (blockIdx.x * blockDim.x + threadIdx.x) >> 6;
    int lane = threadIdx.x & 63;
    for (int w = wid; w < N_NODES * NW; w += nwaves) {
        int i = w >> 6, wc = w & 63;
        int j = (wc << 6) | lane;
        u64 m = __ballot(adj[(size_t)i * N_NODES + j] > 0);
        if (lane == 0) mb[w] = m;
    }
}

// ---------------- fp32 -> bf16 flat convert ----------------
__global__ void cvt4(const float* __restrict__ s, u16* __restrict__ d, int n4) {
    int i = blockIdx.x * blockDim.x + threadIdx.x;
    if (i < n4) {
        float4 v = ((const float4*)s)[i];
        ushort4 o = {bf16u(v.x), bf16u(v.y), bf16u(v.z), bf16u(v.w)};
        ((ushort4*)d)[i] = o;
    }
}

// ---------------- fp32 [rows][ldsrc] (64-col slice) -> bf16 transposed [64][ldd] ----
__global__ __launch_bounds__(256) void to_bf16_T(
    const float* __restrict__ src, int ldsrc, size_t cstep,
    u16* __restrict__ dst, size_t dstep, int ldd) {
    __shared__ alignas(16) u16 T[64][72];
    const int j0 = blockIdx.x * 64;
    const size_t c0 = (size_t)blockIdx.y * cstep;
    u16* d = dst + (size_t)blockIdx.y * dstep;
    const int t = threadIdx.x;
    const int row = t & 63, g = t >> 6;
    #pragma unroll
    for (int k = 0; k < 16; k += 4) {
        float4 v = *(const float4*)(src + (size_t)(j0 + row) * ldsrc + c0 + g * 16 + k);
        T[g * 16 + k + 0][row] = bf16u(v.x);
        T[g * 16 + k + 1][row] = bf16u(v.y);
        T[g * 16 + k + 2][row] = bf16u(v.z);
        T[g * 16 + k + 3][row] = bf16u(v.w);
    }
    __syncthreads();
    const int dd = t >> 2, jc = (t & 3) * 16;
    *(uint4*)(d + (size_t)dd * ldd + j0 + jc) = *(const uint4*)&T[dd][jc];
    *(uint4*)(d + (size_t)dd * ldd + j0 + jc + 8) = *(const uint4*)&T[dd][jc + 8];
}

// ---------------- fused MFMA GEMM (x@W / h@Wo + f1/f2 + gmax + bf16-T out) ----
__global__ __launch_bounds__(256) void gemm_fused(
    const u16* __restrict__ A, int lda, const u16* __restrict__ Bt, int ldb,
    const float* __restrict__ a1a, const float* __restrict__ a2a,
    u16* __restrict__ WhBT, float* __restrict__ f1o, float* __restrict__ f2o,
    unsigned* __restrict__ gmk, int K) {
    __shared__ alignas(16) u16 T[64][72];
    const int t = threadIdx.x, lane = t & 63, wv = t >> 6;
    const int c16 = lane & 15, kg = lane >> 4;
    const int h = blockIdx.x;
    const int bm = blockIdx.y * 64;
    const u16* Ap = A + (size_t)(bm + wv * 16 + c16) * lda + kg * 8;
    const u16* Bp = Bt + (size_t)(h * 64 + c16) * ldb + kg * 8;
    f32x4 acc[4] = {};
    #pragma unroll 4
    for (int k0 = 0; k0 < K; k0 += 32) {
        bf16x8 a = *(const bf16x8*)(Ap + k0);
        #pragma unroll
        for (int ct = 0; ct < 4; ++ct) {
            bf16x8 b = *(const bf16x8*)(Bp + (size_t)ct * 16 * ldb + k0);
            acc[ct] = mfma16(a, b, acc[ct]);
        }
    }
    float a1v[4], a2v[4];
    #pragma unroll
    for (int ct = 0; ct < 4; ++ct) {
        a1v[ct] = a1a[h * 64 + ct * 16 + c16];
        a2v[ct] = a2a[h * 64 + ct * 16 + c16];
    }
    float mx = -1e30f;
    #pragma unroll
    for (int r = 0; r < 4; ++r) {
        float s1 = 0.f, s2 = 0.f;
        int rl = wv * 16 + kg * 4 + r;
        #pragma unroll
        for (int ct = 0; ct < 4; ++ct) {
            float v = acc[ct][r];
            s1 = fmaf(v, a1v[ct], s1);
            s2 = fmaf(v, a2v[ct], s2);
            T[ct * 16 + c16][rl] = bf16u(v);
        }
        #pragma unroll
        for (int off = 1; off < 16; off <<= 1) {
            s1 += __shfl_xor(s1, off, 64);
            s2 += __shfl_xor(s2, off, 64);
        }
        if (c16 == 0) {
            f1o[(size_t)h * N_NODES + bm + rl] = s1;
            f2o[(size_t)h * N_NODES + bm + rl] = s2;
        }
        mx = fmaxf(mx, s2);
    }
    mx = fmaxf(mx, __shfl_xor(mx, 16, 64));
    mx = fmaxf(mx, __shfl_xor(mx, 32, 64));
    if (lane == 0) atomicMax(&gmk[h], fkey(mx));
    __syncthreads();
    const int dd = t >> 2, jc = (t & 3) * 16;
    u16* dst = WhBT + (size_t)(h * 64 + dd) * N_NODES + bm;
    *(uint4*)(dst + jc) = *(const uint4*)&T[dd][jc];
    *(uint4*)(dst + jc + 8) = *(const uint4*)&T[dd][jc + 8];
}

// ---------------- per-row / per-col softmax coefficients ----------------
__global__ void coefk(const float* __restrict__ f1, const float* __restrict__ f2,
                      const unsigned* __restrict__ gmk, float4* __restrict__ rowc,
                      float2* __restrict__ uv) {
    int h = blockIdx.y;
    int i = blockIdx.x * 256 + threadIdx.x;
    float g = funkey(gmk[h]);
    float a = f1[(size_t)h * N_NODES + i];
    float s = a + g;
    float M = lrelu02(s);
    rowc[(size_t)h * N_NODES + i] = make_float4(__expf(s - M), __expf(0.2f * s - M), 0.f, 0.f);
    float b = f2[(size_t)h * N_NODES + i] - g;
    uv[(size_t)h * N_NODES + i] = make_float2(__expf(b), __expf(0.2f * b));
}

// ---------------- attention v3: prefetched, j-split, partial outputs ----------
// OUTF 1: fp32 row-major partial [js][4096][512] (NH=8)
// OUTF 3: fp32 transposed partial [js][64][4096]  (NH=1)
template <int NH, int ROWS, int JSPLIT, int OUTF>
__global__ __launch_bounds__(256) void attn_v3(
    const u16* __restrict__ WhB, const float2* __restrict__ uv,
    const float4* __restrict__ rowc, const u64* __restrict__ mb,
    float* __restrict__ outp, float* __restrict__ denP) {
    constexpr int NQ = ROWS / 4;
    constexpr int NMT = ROWS / 16;
    constexpr int NJT = (N_NODES / 64) / JSPLIT;
    __shared__ alignas(16) u16 pS[2][ROWS][64];
    __shared__ float Tof[(OUTF == 3) ? 64 * 33 : 1];
    const int b = blockIdx.x;
    int h, ib, js;
    if (NH == 8) { h = b & 7; int r = b >> 3; js = r % JSPLIT; ib = r / JSPLIT; }
    else { h = 0; js = b % JSPLIT; ib = b / JSPLIT; }
    const int i0 = ib * ROWS;
    const int jt0 = js * NJT;
    const int t = threadIdx.x, lane = t & 63, wv = t >> 6;
    const int wv_u = __builtin_amdgcn_readfirstlane(wv);

    const float2* __restrict__ uvp = uv + (size_t)h * N_NODES;
    const float4* __restrict__ rcp = rowc + (size_t)h * N_NODES;
    const u64* __restrict__ mbp = mb + (size_t)(i0 + wv_u) * NW + jt0;

    float Aq[NQ], Bq[NQ], den[NQ];
    #pragma unroll
    for (int q = 0; q < NQ; ++q) {
        float4 rc = rcp[i0 + q * 4 + wv];
        Aq[q] = rc.x; Bq[q] = rc.y; den[q] = 0.f;
    }
    const int wcE = lane ^ (wv << 3);
    const int wcO = lane ^ ((wv + 4) << 3);
    const int kg = lane >> 4, c16 = lane & 15;
    const int ocol = wv * 16 + c16;
    const u16* bptr = WhB + ((size_t)h * 64 + ocol) * N_NODES + jt0 * 64 + kg * 8;
    const int sw8 = (c16 & 7) << 3;
    f32x4 acc[NMT] = {};

    // prologue: tile 0 operands in registers
    bf16x8 b0 = *(const bf16x8*)(bptr);
    bf16x8 b1 = *(const bf16x8*)(bptr + 32);
    float2 uvv = uvp[jt0 * 64 + lane];
    u64 m[NQ];
    #pragma unroll
    for (int q = 0; q < NQ; ++q) m[q] = mbp[q * 4 * NW];

    for (int it = 0; it < NJT; ++it) {
        const int buf = it & 1;
        const int nit = (it + 1 < NJT) ? it + 1 : it;
        // prefetch next tile (consumed next iteration; latency hides here)
        bf16x8 nb0 = *(const bf16x8*)(bptr + (size_t)nit * 64);
        bf16x8 nb1 = *(const bf16x8*)(bptr + (size_t)nit * 64 + 32);
        float2 nuv = uvp[(jt0 + nit) * 64 + lane];
        u64 nm[NQ];
        #pragma unroll
        for (int q = 0; q < NQ; ++q) nm[q] = mbp[q * 4 * NW + nit];
        // p-phase on current registers
        #pragma unroll
        for (int q = 0; q < NQ; ++q) {
            unsigned wlo = __builtin_amdgcn_readfirstlane((unsigned)m[q]);
            unsigned whi = __builtin_amdgcn_readfirstlane((unsigned)(m[q] >> 32));
            u64 ws = ((u64)whi << 32) | wlo;
            float tv = fmaxf(Aq[q] * uvv.x, Bq[q] * uvv.y);
            float p;
            asm("v_cndmask_b32 %0, 0, %1, %2" : "=v"(p) : "v"(tv), "s"(ws));
            den[q] += p;
            pS[buf][q * 4 + wv][(q & 1) ? wcO : wcE] = bf16u(p);
        }
        __syncthreads();
        __builtin_amdgcn_s_setprio(1);
        #pragma unroll
        for (int mt = 0; mt < NMT; ++mt) {
            const u16* ap = &pS[buf][mt * 16 + c16][0];
            bf16x8 a0 = *(const bf16x8*)&ap[(kg * 8) ^ sw8];
            bf16x8 a1 = *(const bf16x8*)&ap[(32 + kg * 8) ^ sw8];
            acc[mt] = mfma16(a0, b0, acc[mt]);
            acc[mt] = mfma16(a1, b1, acc[mt]);
        }
        __builtin_amdgcn_s_setprio(0);
        b0 = nb0; b1 = nb1; uvv = nuv;
        #pragma unroll
        for (int q = 0; q < NQ; ++q) m[q] = nm[q];
    }

    #pragma unroll
    for (int q = 0; q < NQ; ++q) {
        float s = den[q];
        #pragma unroll
        for (int off = 32; off; off >>= 1) s += __shfl_xor(s, off, 64);
        den[q] = s;
    }

    if constexpr (OUTF == 1) {
        if (lane == 0) {
            #pragma unroll
            for (int q = 0; q < NQ; ++q)
                denP[(size_t)js * (8 * N_NODES) + (size_t)h * N_NODES + i0 + q * 4 + wv] = den[q];
        }
        float* dst = outp + (size_t)js * N_NODES * 512;
        #pragma unroll
        for (int mt = 0; mt < NMT; ++mt)
            #pragma unroll
            for (int r = 0; r < 4; ++r)
                dst[(size_t)(i0 + mt * 16 + kg * 4 + r) * 512 + h * 64 + ocol] = acc[mt][r];
    } else {
        if (lane == 0) {
            #pragma unroll
            for (int q = 0; q < NQ; ++q)
                denP[(size_t)js * N_NODES + i0 + q * 4 + wv] = den[q];
        }
        #pragma unroll
        for (int mt = 0; mt < NMT; ++mt)
            #pragma unroll
            for (int r = 0; r < 4; ++r)
                Tof[ocol * 33 + mt * 16 + kg * 4 + r] = acc[mt][r];
        __syncthreads();
        const int c = t >> 2, r0 = (t & 3) * 8;
        float* dst = outp + (size_t)js * 64 * N_NODES + (size_t)c * N_NODES + i0 + r0;
        float4 v0 = {Tof[c * 33 + r0 + 0], Tof[c * 33 + r0 + 1],
                     Tof[c * 33 + r0 + 2], Tof[c * 33 + r0 + 3]};
        float4 v1 = {Tof[c * 33 + r0 + 4], Tof[c * 33 + r0 + 5],
                     Tof[c * 33 + r0 + 6], Tof[c * 33 + r0 + 7]};
        *(float4*)(dst) = v0;
        *(float4*)(dst + 4) = v1;
    }
}

// ---------------- combine attn8 partials -> bf16 hB ----------------
__global__ __launch_bounds__(256) void combine8(
    const float* __restrict__ part, const float* __restrict__ denp,
    u16* __restrict__ hB) {
    const int t4 = (blockIdx.x * 256 + threadIdx.x) * 4;
    const int i = t4 >> 9, c = t4 & 511, h = c >> 6;
    float4 p0 = *(const float4*)(part + t4);
    float4 p1 = *(const float4*)(part + (size_t)N_NODES * 512 + t4);
    float d = denp[h * N_NODES + i] + denp[8 * N_NODES + h * N_NODES + i];
    float inv = d > 0.f ? 1.f / d : 0.f;
    float v[4] = {(p0.x + p1.x) * inv, (p0.y + p1.y) * inv,
                  (p0.z + p1.z) * inv, (p0.w + p1.w) * inv};
    ushort4 o;
    #pragma unroll
    for (int k = 0; k < 4; ++k) {
        float e = v[k] > 0.f ? v[k] : expm1f(v[k]);
        ((u16*)&o)[k] = bf16u(e);
    }
    *(ushort4*)(hB + t4) = o;
}

// ---------------- combine attn1 partials + ELU + log_softmax -> bf16 lsT ------
__global__ __launch_bounds__(256) void combine1_lsm(
    const float* __restrict__ partT, const float* __restrict__ denp,
    u16* __restrict__ lsT) {
    __shared__ float vb[N_NODES];
    __shared__ float r[256];
    const int c = blockIdx.x, t = threadIdx.x;
    float m = -1e30f;
    for (int i = t * 4; i < N_NODES; i += 1024) {
        float4 s = {0.f, 0.f, 0.f, 0.f}, d = {0.f, 0.f, 0.f, 0.f};
        #pragma unroll
        for (int js = 0; js < 4; ++js) {
            float4 pv = *(const float4*)(partT + (size_t)js * 64 * N_NODES +
                                         (size_t)c * N_NODES + i);
            float4 dv = *(const float4*)(denp + (size_t)js * N_NODES + i);
            s.x += pv.x; s.y += pv.y; s.z += pv.z; s.w += pv.w;
            d.x += dv.x; d.y += dv.y; d.z += dv.z; d.w += dv.w;
        }
        float vv[4] = {d.x > 0.f ? s.x / d.x : 0.f, d.y > 0.f ? s.y / d.y : 0.f,
                       d.z > 0.f ? s.z / d.z : 0.f, d.w > 0.f ? s.w / d.w : 0.f};
        #pragma unroll
        for (int k = 0; k < 4; ++k) {
            float e = vv[k] > 0.f ? vv[k] : expm1f(vv[k]);
            vb[i + k] = e;
            m = fmaxf(m, e);
        }
    }
    r[t] = m;
    __syncthreads();
    for (int s = 128; s; s >>= 1) {
        if (t < s) r[t] = fmaxf(r[t], r[t + s]);
        __syncthreads();
    }
    m = r[0];
    __syncthreads();
    float sum = 0.f;
    for (int i = t; i < N_NODES; i += 256) sum += __expf(vb[i] - m);
    r[t] = sum;
    __syncthreads();
    for (int s = 128; s; s >>= 1) {
        if (t < s) r[t] += r[t + s];
        __syncthreads();
    }
    float lse = m + __logf(r[0]);
    for (int i = t * 4; i < N_NODES; i += 1024) {
        ushort4 o = {bf16u(vb[i] - lse), bf16u(vb[i + 1] - lse),
                     bf16u(vb[i + 2] - lse), bf16u(vb[i + 3] - lse)};
        *(ushort4*)(lsT + (size_t)c * N_NODES + i) = o;
    }
}

// ---------------- mlp1: split-K MFMA  part[ks][64 c][512 o] ----------------
__global__ __launch_bounds__(256) void mlp1_mfma(
    const u16* __restrict__ lsT, const u16* __restrict__ W1B,
    float* __restrict__ part) {
    const int t = threadIdx.x, lane = t & 63, wv = t >> 6;
    const int c16 = lane & 15, kg = lane >> 4;
    const int ks = blockIdx.x & 15;
    const int bn = (blockIdx.x >> 4) * 64;
    const int kb = ks * 256;
    const u16* Ap = lsT + (size_t)(wv * 16 + c16) * N_NODES + kb + kg * 8;
    const u16* Bp = W1B + (size_t)(bn + c16) * N_NODES + kb + kg * 8;
    f32x4 acc[4] = {};
    #pragma unroll
    for (int k0 = 0; k0 < 256; k0 += 32) {
        bf16x8 a = *(const bf16x8*)(Ap + k0);
        #pragma unroll
        for (int ct = 0; ct < 4; ++ct) {
            bf16x8 b = *(const bf16x8*)(Bp + (size_t)ct * 16 * N_NODES + k0);
            acc[ct] = mfma16(a, b, acc[ct]);
        }
    }
    float* dst = part + (size_t)ks * 64 * 512;
    #pragma unroll
    for (int ct = 0; ct < 4; ++ct)
        #pragma unroll
        for (int r = 0; r < 4; ++r)
            dst[(size_t)(wv * 16 + kg * 4 + r) * 512 + bn + ct * 16 + c16] = acc[ct][r];
}

__global__ void mlp1_fin(const float* __restrict__ part, const float* __restrict__ b1,
                         float* __restrict__ y1) {
    int idx = blockIdx.x * 256 + threadIdx.x;
    int o = idx & 511;
    float s = 0.f;
    #pragma unroll
    for (int ks = 0; ks < 16; ++ks) s += part[(size_t)ks * 32768 + idx];
    s += b1[o];
    y1[idx] = s > 0.f ? s : 0.1f * s;
}

// ---------------- mlp2 ----------------
__global__ __launch_bounds__(256) void mlp2(
    const float* __restrict__ y1, const float* __restrict__ W2,
    const float* __restrict__ b2, float* __restrict__ out) {
    __shared__ alignas(16) float row[512];
    int c = blockIdx.x, t = threadIdx.x;
    row[t] = y1[(size_t)c * 512 + t];
    row[t + 256] = y1[(size_t)c * 512 + t + 256];
    __syncthreads();
    float acc = 0.f;
    #pragma unroll 4
    for (int o = 0; o < 512; o += 4) {
        float4 w4 = *(const float4*)(W2 + (size_t)t * 512 + o);
        float4 r4 = *(const float4*)(&row[o]);
        acc += w4.x * r4.x + w4.y * r4.y + w4.z * r4.z + w4.w * r4.w;
    }
    out[(size_t)c * 256 + t] = acc + b2[t];
}

extern "C" void kernel_launch(void* const* d_in, const int* in_sizes, int n_in,
                              void* d_out, int out_size, void* d_ws, size_t ws_size,
                              hipStream_t stream) {
    const float* x   = (const float*)d_in[0];
    const int*   adj = (const int*)d_in[1];
    const float* W   = (const float*)d_in[2];
    const float* a1  = (const float*)d_in[3];
    const float* a2  = (const float*)d_in[4];
    const float* Wo  = (const float*)d_in[5];
    const float* ao1 = (const float*)d_in[6];
    const float* ao2 = (const float*)d_in[7];
    const float* W1  = (const float*)d_in[8];
    const float* b1  = (const float*)d_in[9];
    const float* W2  = (const float*)d_in[10];
    const float* b2  = (const float*)d_in[11];
    float* out = (float*)d_out;

    char* ws = (char*)d_ws;
    size_t off = 0;
    auto alloc = [&](size_t bytes) {
        void* p = ws + off;
        off += (bytes + 255) & ~(size_t)255;
        return p;
    };
    u64*     mb     = (u64*)alloc((size_t)N_NODES * NW * 8);
    u16*     xB     = (u16*)alloc((size_t)N_NODES * FIN * 2);
    u16*     WBt    = (u16*)alloc((size_t)NHEAD * DHEAD * FIN * 2);
    u16*     WoBt   = (u16*)alloc((size_t)DHEAD * FIN * 2);
    u16*     W1B    = (u16*)alloc((size_t)512 * N_NODES * 2);
    u16*     WhB    = (u16*)alloc((size_t)NHEAD * DHEAD * N_NODES * 2);
    u16*     WhoB   = (u16*)alloc((size_t)DHEAD * N_NODES * 2);
    u16*     hB     = (u16*)alloc((size_t)N_NODES * 512 * 2);
    float*   part8  = (float*)alloc((size_t)2 * N_NODES * 512 * 4);   // 16 MB
    float*   den8   = (float*)alloc((size_t)2 * 8 * N_NODES * 4);
    float*   partT1 = (float*)alloc((size_t)4 * 64 * N_NODES * 4);    // 4 MB
    float*   den1   = (float*)alloc((size_t)4 * N_NODES * 4);
    u16*     lsT    = (u16*)alloc((size_t)64 * N_NODES * 2);
    float*   part   = (float*)alloc((size_t)16 * 64 * 512 * 4);
    float*   f1b    = (float*)alloc((size_t)9 * N_NODES * 4);
    float*   f2b    = (float*)alloc((size_t)9 * N_NODES * 4);
    unsigned* gmk   = (unsigned*)alloc(16 * 4);
    float4*  rowc   = (float4*)alloc((size_t)9 * N_NODES * 16);
    float2*  uvb    = (float2*)alloc((size_t)9 * N_NODES * 8);
    float*   y1     = (float*)alloc((size_t)64 * 512 * 4);
    (void)ws_size; (void)in_sizes; (void)n_in; (void)out_size;

    pack_mask<<<1024, 256, 0, stream>>>(adj, mb, gmk);
    cvt4<<<(N_NODES * FIN / 4 + 255) / 256, 256, 0, stream>>>(x, xB, N_NODES * FIN / 4);
    cvt4<<<(512 * N_NODES / 4 + 255) / 256, 256, 0, stream>>>(W1, W1B, 512 * N_NODES / 4);
    to_bf16_T<<<dim3(8, 8), 256, 0, stream>>>(W, 64, (size_t)FIN * DHEAD, WBt,
                                              (size_t)DHEAD * FIN, FIN);
    to_bf16_T<<<dim3(8, 1), 256, 0, stream>>>(Wo, 64, 0, WoBt, 0, FIN);
    // layer 1
    gemm_fused<<<dim3(8, 64), 256, 0, stream>>>(xB, FIN, WBt, FIN, a1, a2,
                                                WhB, f1b, f2b, gmk, FIN);
    coefk<<<dim3(16, 8), 256, 0, stream>>>(f1b, f2b, gmk, rowc, uvb);
    attn_v3<8, 64, 2, 1><<<(N_NODES / 64) * 2 * 8, 256, 0, stream>>>(
        WhB, uvb, rowc, mb, part8, den8);
    combine8<<<N_NODES * 512 / 4 / 256, 256, 0, stream>>>(part8, den8, hB);
    // layer 2
    gemm_fused<<<dim3(1, 64), 256, 0, stream>>>(hB, 512, WoBt, FIN, ao1, ao2,
                                                WhoB, f1b + (size_t)8 * N_NODES,
                                                f2b + (size_t)8 * N_NODES, gmk + 8, FIN);
    coefk<<<dim3(16, 1), 256, 0, stream>>>(f1b + (size_t)8 * N_NODES,
                                           f2b + (size_t)8 * N_NODES, gmk + 8,
                                           rowc + (size_t)8 * N_NODES,
                                           uvb + (size_t)8 * N_NODES);
    attn_v3<1, 32, 4, 3><<<(N_NODES / 32) * 4, 256, 0, stream>>>(
        WhoB, uvb + (size_t)8 * N_NODES, rowc + (size_t)8 * N_NODES, mb, partT1, den1);
    combine1_lsm<<<64, 256, 0, stream>>>(partT1, den1, lsT);
    // MLP head
    mlp1_mfma<<<128, 256, 0, stream>>>(lsT, W1B, part);
    mlp1_fin<<<128, 256, 0, stream>>>(part, b1, y1);
    mlp2<<<64, 256, 0, stream>>>(y1, W2, b2, out);
}